// Round 2
// baseline (578.279 us; speedup 1.0000x reference)
//
#include <hip/hip_runtime.h>
#include <hip/hip_bf16.h>

#define NEG_SLOPE 0.2f
#define BN_RS 0.9999950000374997f   // 1/sqrt(1 + 1e-5)

__device__ __forceinline__ void load8(const float* p, float* o) {
  float4 v0 = *(const float4*)p;
  float4 v1 = *(const float4*)(p + 4);
  o[0]=v0.x; o[1]=v0.y; o[2]=v0.z; o[3]=v0.w;
  o[4]=v1.x; o[5]=v1.y; o[6]=v1.z; o[7]=v1.w;
}

// ---------------- CSR build ----------------

__global__ void deg_init(int* deg, int N) {
  int i = blockIdx.x * 256 + threadIdx.x;
  if (i < N) deg[i] = 1;             // self-loop
}
__global__ void deg_count(const int* __restrict__ ei, int* deg, int E) {
  int i = blockIdx.x * 256 + threadIdx.x;
  if (i < E) atomicAdd(&deg[ei[E + i]], 1);
}
__global__ void scan1(const int* __restrict__ deg, int* __restrict__ inc,
                      int* __restrict__ bsum, int N) {
  __shared__ int sd[256];
  int tid = threadIdx.x;
  int i = blockIdx.x * 256 + tid;
  int v = (i < N) ? deg[i] : 0;
  sd[tid] = v;
  __syncthreads();
  for (int off = 1; off < 256; off <<= 1) {
    int t = (tid >= off) ? sd[tid - off] : 0;
    __syncthreads();
    sd[tid] += t;
    __syncthreads();
  }
  if (i < N) inc[i] = sd[tid];
  if (tid == 255) bsum[blockIdx.x] = sd[255];
}
__global__ void scan2(int* bsum, int nb) {  // nb <= 256
  __shared__ int sd[256];
  int tid = threadIdx.x;
  int v = (tid < nb) ? bsum[tid] : 0;
  sd[tid] = v;
  __syncthreads();
  for (int off = 1; off < 256; off <<= 1) {
    int t = (tid >= off) ? sd[tid - off] : 0;
    __syncthreads();
    sd[tid] += t;
    __syncthreads();
  }
  if (tid < nb) bsum[tid] = sd[tid] - v;   // exclusive
}
__global__ void scan3(const int* __restrict__ inc, const int* __restrict__ deg,
                      const int* __restrict__ bsum, int* __restrict__ rowptr,
                      int* __restrict__ pos, int N) {
  int i = blockIdx.x * 256 + threadIdx.x;
  if (i < N) {
    int r = inc[i] + bsum[blockIdx.x];
    rowptr[i + 1] = r;
    pos[i] = r - deg[i];
    if (i == 0) rowptr[0] = 0;
  }
}
__global__ void scatter_e(const int* __restrict__ ei, int* pos,
                          int* __restrict__ csr, int E) {
  int i = blockIdx.x * 256 + threadIdx.x;
  if (i < E) {
    int s = ei[i], d = ei[E + i];
    int p = atomicAdd(&pos[d], 1);
    csr[p] = s;
  }
}
__global__ void scatter_l(int* pos, int* __restrict__ csr, int N) {
  int i = blockIdx.x * 256 + threadIdx.x;
  if (i < N) {
    int p = atomicAdd(&pos[i], 1);
    csr[p] = i;
  }
}

// ---------------- GEMM: C[N x P] = A[N x K] @ W[K x P], fp32 ----------------
// EPI 0: plain store. EPI 1: bn(relu(acc + bias)) with gamma/beta.
template <int P, int EPI>
__global__ __launch_bounds__(256) void gemm_k(
    const float* __restrict__ A, const float* __restrict__ W, float* __restrict__ C,
    int N, int K, const float* __restrict__ bias,
    const float* __restrict__ gamma, const float* __restrict__ beta) {
  constexpr int TC = P / 16;          // cols per thread (8 or 4)
  __shared__ float As[16][132];       // transposed A tile, padded (16B-aligned rows)
  __shared__ float Ws[16][P];
  const int tid = threadIdx.x;
  const int row0 = blockIdx.x * 128;
  const int tr = tid & 15;            // rows 8*tr .. 8*tr+7
  const int tc = tid >> 4;            // cols TC*tc ..
  float acc[8][TC];
#pragma unroll
  for (int i = 0; i < 8; i++)
#pragma unroll
    for (int j = 0; j < TC; j++) acc[i][j] = 0.f;

  const int arow = tid >> 1;          // 0..127
  const int ahalf = (tid & 1) * 8;    // 0 or 8
  const int nk = K >> 4;
  for (int kc = 0; kc < nk; ++kc) {
    // stage A (transposed into LDS)
    float av[8];
    int gr = row0 + arow;
    if (gr < N) {
      load8(A + (size_t)gr * K + kc * 16 + ahalf, av);
    } else {
#pragma unroll
      for (int i = 0; i < 8; i++) av[i] = 0.f;
    }
#pragma unroll
    for (int i = 0; i < 8; i++) As[ahalf + i][arow] = av[i];
    // stage W
    if (P == 128) {
      int k = tid >> 4;
      int j = (tid & 15) * 8;
      float wv[8];
      load8(W + (size_t)(kc * 16 + k) * P + j, wv);
#pragma unroll
      for (int i = 0; i < 8; i++) Ws[k][j + i] = wv[i];
    } else {  // P == 64
      int k = tid >> 4;
      int j = (tid & 15) * 4;
      float4 u = *(const float4*)(W + (size_t)(kc * 16 + k) * P + j);
      Ws[k][j + 0] = u.x; Ws[k][j + 1] = u.y;
      Ws[k][j + 2] = u.z; Ws[k][j + 3] = u.w;
    }
    __syncthreads();
#pragma unroll
    for (int k = 0; k < 16; k++) {
      float a[8];
      float4 t0 = *(const float4*)&As[k][8 * tr];
      float4 t1 = *(const float4*)&As[k][8 * tr + 4];
      a[0]=t0.x; a[1]=t0.y; a[2]=t0.z; a[3]=t0.w;
      a[4]=t1.x; a[5]=t1.y; a[6]=t1.z; a[7]=t1.w;
      float w[TC];
#pragma unroll
      for (int q = 0; q < TC / 4; q++) {
        float4 wv = *(const float4*)&Ws[k][TC * tc + 4 * q];
        w[4*q]=wv.x; w[4*q+1]=wv.y; w[4*q+2]=wv.z; w[4*q+3]=wv.w;
      }
#pragma unroll
      for (int i = 0; i < 8; i++)
#pragma unroll
        for (int j = 0; j < TC; j++) acc[i][j] = fmaf(a[i], w[j], acc[i][j]);
    }
    __syncthreads();
  }
#pragma unroll
  for (int i = 0; i < 8; i++) {
    int r = row0 + 8 * tr + i;
    if (r < N) {
#pragma unroll
      for (int j = 0; j < TC; j++) {
        int c = TC * tc + j;
        float v = acc[i][j];
        if (EPI == 1) {
          v += bias[c];
          v = v > 0.f ? v : 0.f;
          v = v * (gamma[c] * BN_RS) + beta[c];
        }
        C[(size_t)r * P + c] = v;
      }
    }
  }
}

// ---------------- attention scores: es/ed[n][h] = <h_row, a_s/a_d> ----------------
__global__ __launch_bounds__(256) void attn_scores(
    const float* __restrict__ hx, const float* __restrict__ as_,
    const float* __restrict__ ad_, float* __restrict__ es, float* __restrict__ ed,
    int N) {
  int t = blockIdx.x * 256 + threadIdx.x;   // n*4 + h
  if (t >= N * 4) return;
  int h = t & 3;
  const float* row = hx + (size_t)(t >> 2) * 128 + h * 32;
  float s = 0.f, d = 0.f;
#pragma unroll
  for (int q = 0; q < 8; q++) {
    float4 hv = *(const float4*)(row + 4 * q);
    float4 ua = *(const float4*)(as_ + h * 32 + 4 * q);
    float4 ud = *(const float4*)(ad_ + h * 32 + 4 * q);
    s += hv.x*ua.x + hv.y*ua.y + hv.z*ua.z + hv.w*ua.w;
    d += hv.x*ud.x + hv.y*ud.y + hv.z*ud.z + hv.w*ud.w;
  }
  es[t] = s; ed[t] = d;
}

// ---------------- GAT aggregation: one wave per dst node ----------------
// lane i holds features (2i, 2i+1); head = i>>4. All 16 lanes of a head group
// compute identical w and z, so normalization needs no reduction.
// MODE 0: out fp32 [N,128] = relu(S/z + bias)  (concat)
// MODE 1: out fp32 [N,32]  = mean_heads(S/z) + bias  (no relu)
template <int MODE>
__global__ __launch_bounds__(256) void gat_agg(
    const float* __restrict__ hx, const int* __restrict__ rowptr,
    const int* __restrict__ csr, const float* __restrict__ es,
    const float* __restrict__ ed, const float* __restrict__ bias,
    float* __restrict__ outp, int N) {
  int wid = (blockIdx.x * 256 + threadIdx.x) >> 6;
  if (wid >= N) return;
  int lane = threadIdx.x & 63;
  int beg = rowptr[wid], end = rowptr[wid + 1];
  int head = lane >> 4;
  float edv = ed[wid * 4 + head];
  float ax = 0.f, ay = 0.f, z = 0.f;
  int s_next = csr[beg];              // deg >= 1 always (self-loop)
  for (int e = beg; e < end; ++e) {
    int s = s_next;
    if (e + 1 < end) s_next = csr[e + 1];
    float t = es[s * 4 + head] + edv;
    t = t > 0.f ? t : NEG_SLOPE * t;  // leaky_relu
    float w = __expf(t);              // no max-shift needed: |t| small
    float2 hv = *(const float2*)(hx + (size_t)s * 128 + 2 * lane);
    ax = fmaf(w, hv.x, ax);
    ay = fmaf(w, hv.y, ay);
    z += w;
  }
  float inv = 1.f / (z + 1e-16f);
  float vx = ax * inv, vy = ay * inv;
  if (MODE == 0) {
    vx += bias[2 * lane]; vy += bias[2 * lane + 1];
    vx = vx > 0.f ? vx : 0.f;  vy = vy > 0.f ? vy : 0.f;
    *(float2*)(outp + (size_t)wid * 128 + 2 * lane) = make_float2(vx, vy);
  } else {
    vx += __shfl_xor(vx, 16); vx += __shfl_xor(vx, 32);
    vy += __shfl_xor(vy, 16); vy += __shfl_xor(vy, 32);
    if (lane < 16) {
      float ox = vx * 0.25f + bias[2 * lane];
      float oy = vy * 0.25f + bias[2 * lane + 1];
      *(float2*)(outp + (size_t)wid * 32 + 2 * lane) = make_float2(ox, oy);
    }
  }
}

extern "C" void kernel_launch(void* const* d_in, const int* in_sizes, int n_in,
                              void* d_out, int out_size, void* d_ws, size_t ws_size,
                              hipStream_t stream) {
  const float* x   = (const float*)d_in[0];
  const int*   ei  = (const int*)d_in[1];
  const float* W1  = (const float*)d_in[2];
  const float* a1s = (const float*)d_in[3];
  const float* a1d = (const float*)d_in[4];
  const float* b1  = (const float*)d_in[5];
  const float* W2  = (const float*)d_in[6];
  const float* a2s = (const float*)d_in[7];
  const float* a2d = (const float*)d_in[8];
  const float* b2  = (const float*)d_in[9];
  const float* M1w = (const float*)d_in[10];
  const float* M1b = (const float*)d_in[11];
  const float* g1  = (const float*)d_in[12];
  const float* be1 = (const float*)d_in[13];
  const float* M2w = (const float*)d_in[14];
  const float* M2b = (const float*)d_in[15];
  const float* g2  = (const float*)d_in[16];
  const float* be2 = (const float*)d_in[17];
  const float* W3  = (const float*)d_in[18];
  const float* a3s = (const float*)d_in[19];
  const float* a3d = (const float*)d_in[20];
  const float* b3  = (const float*)d_in[21];

  const int N = in_sizes[0] / 128;
  const int E = in_sizes[1] / 2;

  char* w = (char*)d_ws;
  float* bufA = (float*)w; w += (size_t)N * 128 * 4;
  float* bufB = (float*)w; w += (size_t)N * 128 * 4;
  float* bufM = (float*)w; w += (size_t)N * 64 * 4;
  float* esb  = (float*)w; w += (size_t)N * 4 * 4;
  float* edb  = (float*)w; w += (size_t)N * 4 * 4;
  int* deg    = (int*)w;   w += (size_t)N * 4;
  int* inc    = (int*)w;   w += (size_t)N * 4;
  int* rowptr = (int*)w;   w += (size_t)(N + 1) * 4;
  int* pos    = (int*)w;   w += (size_t)N * 4;
  int* bsum   = (int*)w;   w += 256 * 4;
  int* csr    = (int*)w;   w += (size_t)(E + N) * 4;

  const int nb = (N + 255) / 256;
  const int eb = (E + 255) / 256;
  const int gb = (N + 127) / 128;
  const int ab = (N * 4 + 255) / 256;
  const int aggb = (N + 3) / 4;   // 4 waves per block

  // ---- CSR build (counting sort by dst) ----
  deg_init<<<nb, 256, 0, stream>>>(deg, N);
  deg_count<<<eb, 256, 0, stream>>>(ei, deg, E);
  scan1<<<nb, 256, 0, stream>>>(deg, inc, bsum, N);
  scan2<<<1, 256, 0, stream>>>(bsum, nb);
  scan3<<<nb, 256, 0, stream>>>(inc, deg, bsum, rowptr, pos, N);
  scatter_e<<<eb, 256, 0, stream>>>(ei, pos, csr, E);
  scatter_l<<<nb, 256, 0, stream>>>(pos, csr, N);

  // ---- layer 0: conv0 -> relu -> MLP(bn(relu(.))) x2 ----
  gemm_k<128, 0><<<gb, 256, 0, stream>>>(x, W1, bufA, N, 128, nullptr, nullptr, nullptr);
  attn_scores<<<ab, 256, 0, stream>>>(bufA, a1s, a1d, esb, edb, N);
  gat_agg<0><<<aggb, 256, 0, stream>>>(bufA, rowptr, csr, esb, edb, b1, bufB, N);
  gemm_k<64, 1><<<gb, 256, 0, stream>>>(bufB, M1w, bufM, N, 128, M1b, g1, be1);
  gemm_k<128, 1><<<gb, 256, 0, stream>>>(bufM, M2w, bufA, N, 64, M2b, g2, be2);

  // ---- layer 1: conv1 -> relu ----
  gemm_k<128, 0><<<gb, 256, 0, stream>>>(bufA, W2, bufB, N, 128, nullptr, nullptr, nullptr);
  attn_scores<<<ab, 256, 0, stream>>>(bufB, a2s, a2d, esb, edb, N);
  gat_agg<0><<<aggb, 256, 0, stream>>>(bufB, rowptr, csr, esb, edb, b2, bufA, N);

  // ---- layer 2: conv2, mean over heads, +b3 (no relu) ----
  gemm_k<128, 0><<<gb, 256, 0, stream>>>(bufA, W3, bufB, N, 128, nullptr, nullptr, nullptr);
  attn_scores<<<ab, 256, 0, stream>>>(bufB, a3s, a3d, esb, edb, N);
  gat_agg<1><<<aggb, 256, 0, stream>>>(bufB, rowptr, csr, esb, edb, b3, (float*)d_out, N);
}

// Round 3
// 554.588 us; speedup vs baseline: 1.0427x; 1.0427x over previous
//
#include <hip/hip_runtime.h>
#include <hip/hip_bf16.h>

#define NEG_SLOPE 0.2f
#define BN_RS 0.9999950000374997f   // 1/sqrt(1 + 1e-5)

typedef __attribute__((ext_vector_type(8))) short short8;   // 8 bf16 (4 VGPR)
typedef __attribute__((ext_vector_type(4))) float f32x4;    // MFMA acc

typedef unsigned short ushort_t;

// split fp32 -> bf16 hi (RNE) + bf16 lo (RNE of residual)
__device__ __forceinline__ void split_bf16(float f, unsigned short& h, unsigned short& l) {
  union { float f; unsigned u; } c; c.f = f;
  unsigned r = c.u + 0x7FFF + ((c.u >> 16) & 1);
  h = (unsigned short)(r >> 16);
  union { unsigned u; float f; } hv; hv.u = ((unsigned)h) << 16;
  float lf = f - hv.f;
  union { float f; unsigned u; } lc; lc.f = lf;
  unsigned rl = lc.u + 0x7FFF + ((lc.u >> 16) & 1);
  l = (unsigned short)(rl >> 16);
}

// ---------------- CSR build ----------------

__global__ void deg_init(int* deg, int N) {
  int i = blockIdx.x * 256 + threadIdx.x;
  if (i < N) deg[i] = 1;             // self-loop
}
__global__ void deg_count(const int* __restrict__ ei, int* deg, int E) {
  int i = blockIdx.x * 256 + threadIdx.x;
  if (i < E) atomicAdd(&deg[ei[E + i]], 1);
}
__global__ void scan1(const int* __restrict__ deg, int* __restrict__ inc,
                      int* __restrict__ bsum, int N) {
  __shared__ int sd[256];
  int tid = threadIdx.x;
  int i = blockIdx.x * 256 + tid;
  int v = (i < N) ? deg[i] : 0;
  sd[tid] = v;
  __syncthreads();
  for (int off = 1; off < 256; off <<= 1) {
    int t = (tid >= off) ? sd[tid - off] : 0;
    __syncthreads();
    sd[tid] += t;
    __syncthreads();
  }
  if (i < N) inc[i] = sd[tid];
  if (tid == 255) bsum[blockIdx.x] = sd[255];
}
__global__ void scan2(int* bsum, int nb) {  // nb <= 256
  __shared__ int sd[256];
  int tid = threadIdx.x;
  int v = (tid < nb) ? bsum[tid] : 0;
  sd[tid] = v;
  __syncthreads();
  for (int off = 1; off < 256; off <<= 1) {
    int t = (tid >= off) ? sd[tid - off] : 0;
    __syncthreads();
    sd[tid] += t;
    __syncthreads();
  }
  if (tid < nb) bsum[tid] = sd[tid] - v;   // exclusive
}
__global__ void scan3(const int* __restrict__ inc, const int* __restrict__ deg,
                      const int* __restrict__ bsum, int* __restrict__ rowptr,
                      int* __restrict__ pos, int N) {
  int i = blockIdx.x * 256 + threadIdx.x;
  if (i < N) {
    int r = inc[i] + bsum[blockIdx.x];
    rowptr[i + 1] = r;
    pos[i] = r - deg[i];
    if (i == 0) rowptr[0] = 0;
  }
}
__global__ void scatter_e(const int* __restrict__ ei, int* pos,
                          int* __restrict__ csr, int E) {
  int i = blockIdx.x * 256 + threadIdx.x;
  if (i < E) {
    int s = ei[i], d = ei[E + i];
    int p = atomicAdd(&pos[d], 1);
    csr[p] = s;
  }
}
__global__ void scatter_l(int* pos, int* __restrict__ csr, int N) {
  int i = blockIdx.x * 256 + threadIdx.x;
  if (i < N) {
    int p = atomicAdd(&pos[i], 1);
    csr[p] = i;
  }
}

// ---------------- weight prep: W[K][P] fp32 -> Wt hi/lo bf16 [P][K] ----------------
__global__ void wprep(const float* __restrict__ W, unsigned short* __restrict__ H,
                      unsigned short* __restrict__ L, int K, int pshift) {
  int i = blockIdx.x * 256 + threadIdx.x;   // i = k*P + p
  int total = K << pshift;
  if (i >= total) return;
  int k = i >> pshift;
  int p = i & ((1 << pshift) - 1);
  unsigned short h, l;
  split_bf16(W[i], h, l);
  H[(size_t)p * K + k] = h;
  L[(size_t)p * K + k] = l;
}

// ---------------- GEMM via split-bf16 MFMA ----------------
// C[N x P] = A[N x K] @ W[K x P];  A fp32, W pre-split bf16 hi/lo transposed [P][K].
// D = Ah@Wh + Ah@Wl + Al@Wh  (single accumulator) -> fp32-class accuracy.
// EPI 0: plain store. EPI 1: bn(relu(acc + bias)).
template <int P, int K, int EPI>
__global__ __launch_bounds__(256) void gemm_mfma(
    const float* __restrict__ A, const unsigned short* __restrict__ WtH,
    const unsigned short* __restrict__ WtL, float* __restrict__ C, int N,
    const float* __restrict__ bias, const float* __restrict__ gamma,
    const float* __restrict__ beta) {
  constexpr int CT = P / 64;      // col-tiles (of 16) per wave
  constexpr int KT = K / 32;      // k-tiles
  __shared__ unsigned short AsH[128][40];   // stride 40 ushorts = 80 B (16B-aligned rows)
  __shared__ unsigned short AsL[128][40];
  __shared__ unsigned short WsH[P][40];
  __shared__ unsigned short WsL[P][40];
  const int tid = threadIdx.x;
  const int wave = tid >> 6;
  const int lane = tid & 63;
  const int quad = lane >> 4;
  const int l16 = lane & 15;
  const int row0 = blockIdx.x * 128;

  f32x4 acc[8][CT];
#pragma unroll
  for (int rt = 0; rt < 8; rt++)
#pragma unroll
    for (int ct = 0; ct < CT; ct++) acc[rt][ct] = (f32x4){0.f, 0.f, 0.f, 0.f};

  for (int kc = 0; kc < KT; ++kc) {
    // ---- stage A tile (128 x 32 fp32 -> split bf16), coalesced float4 loads ----
#pragma unroll
    for (int it = 0; it < 4; ++it) {
      int idx = it * 256 + tid;          // 1024 float4s
      int r = idx >> 3;
      int c4 = (idx & 7) * 4;
      int gr = row0 + r;
      float4 v;
      if (gr < N) v = *(const float4*)(A + (size_t)gr * K + kc * 32 + c4);
      else v = make_float4(0.f, 0.f, 0.f, 0.f);
      unsigned short h0,h1,h2,h3,l0,l1,l2,l3;
      split_bf16(v.x, h0, l0); split_bf16(v.y, h1, l1);
      split_bf16(v.z, h2, l2); split_bf16(v.w, h3, l3);
      *(ushort4*)&AsH[r][c4] = make_ushort4(h0, h1, h2, h3);
      *(ushort4*)&AsL[r][c4] = make_ushort4(l0, l1, l2, l3);
    }
    // ---- stage W tile (P x 32 bf16 hi/lo), contiguous ushort8 loads ----
#pragma unroll
    for (int it = 0; it < P / 64; ++it) {
      int idx = it * 256 + tid;          // P*4 ushort8 chunks
      int p = idx >> 2;
      int c8 = (idx & 3) * 8;
      short8 vh = *(const short8*)(WtH + (size_t)p * K + kc * 32 + c8);
      short8 vl = *(const short8*)(WtL + (size_t)p * K + kc * 32 + c8);
      *(short8*)&WsH[p][c8] = vh;
      *(short8*)&WsL[p][c8] = vl;
    }
    __syncthreads();

    // ---- B fragments for this k-tile ----
    short8 bh[CT], bl[CT];
#pragma unroll
    for (int ct = 0; ct < CT; ++ct) {
      int n = wave * (16 * CT) + ct * 16 + l16;
      bh[ct] = *(const short8*)&WsH[n][quad * 8];
      bl[ct] = *(const short8*)&WsL[n][quad * 8];
    }
    // ---- MFMA over 8 row-tiles ----
#pragma unroll
    for (int rt = 0; rt < 8; ++rt) {
      int m = rt * 16 + l16;
      short8 ah = *(const short8*)&AsH[m][quad * 8];
      short8 al = *(const short8*)&AsL[m][quad * 8];
#pragma unroll
      for (int ct = 0; ct < CT; ++ct) {
        acc[rt][ct] = __builtin_amdgcn_mfma_f32_16x16x32_bf16(ah, bh[ct], acc[rt][ct], 0, 0, 0);
        acc[rt][ct] = __builtin_amdgcn_mfma_f32_16x16x32_bf16(al, bh[ct], acc[rt][ct], 0, 0, 0);
        acc[rt][ct] = __builtin_amdgcn_mfma_f32_16x16x32_bf16(ah, bl[ct], acc[rt][ct], 0, 0, 0);
      }
    }
    __syncthreads();
  }

  // ---- epilogue: C/D layout col=lane&15, row=quad*4+reg ----
#pragma unroll
  for (int ct = 0; ct < CT; ++ct) {
    int c = wave * (16 * CT) + ct * 16 + l16;
    float bi = 0.f, ga = 0.f, be = 0.f;
    if (EPI == 1) { bi = bias[c]; ga = gamma[c] * BN_RS; be = beta[c]; }
#pragma unroll
    for (int rt = 0; rt < 8; ++rt) {
#pragma unroll
      for (int g = 0; g < 4; ++g) {
        int r = row0 + rt * 16 + quad * 4 + g;
        if (r < N) {
          float v = acc[rt][ct][g];
          if (EPI == 1) {
            v += bi;
            v = v > 0.f ? v : 0.f;
            v = v * ga + be;
          }
          C[(size_t)r * P + c] = v;
        }
      }
    }
  }
}

// ---------------- attention scores: es/ed[n][h] = <h_row, a_s/a_d> ----------------
__global__ __launch_bounds__(256) void attn_scores(
    const float* __restrict__ hx, const float* __restrict__ as_,
    const float* __restrict__ ad_, float* __restrict__ es, float* __restrict__ ed,
    int N) {
  int t = blockIdx.x * 256 + threadIdx.x;   // n*4 + h
  if (t >= N * 4) return;
  int h = t & 3;
  const float* row = hx + (size_t)(t >> 2) * 128 + h * 32;
  float s = 0.f, d = 0.f;
#pragma unroll
  for (int q = 0; q < 8; q++) {
    float4 hv = *(const float4*)(row + 4 * q);
    float4 ua = *(const float4*)(as_ + h * 32 + 4 * q);
    float4 ud = *(const float4*)(ad_ + h * 32 + 4 * q);
    s += hv.x*ua.x + hv.y*ua.y + hv.z*ua.z + hv.w*ua.w;
    d += hv.x*ud.x + hv.y*ud.y + hv.z*ud.z + hv.w*ud.w;
  }
  es[t] = s; ed[t] = d;
}

// ---------------- GAT aggregation: one wave per dst node ----------------
// lane i holds features (2i, 2i+1); head = i>>4. All 16 lanes of a head group
// compute identical w and z, so normalization needs no reduction.
// MODE 0: out fp32 [N,128] = relu(S/z + bias)  (concat)
// MODE 1: out fp32 [N,32]  = mean_heads(S/z) + bias  (no relu)
template <int MODE>
__global__ __launch_bounds__(256) void gat_agg(
    const float* __restrict__ hx, const int* __restrict__ rowptr,
    const int* __restrict__ csr, const float* __restrict__ es,
    const float* __restrict__ ed, const float* __restrict__ bias,
    float* __restrict__ outp, int N) {
  int wid = (blockIdx.x * 256 + threadIdx.x) >> 6;
  if (wid >= N) return;
  int lane = threadIdx.x & 63;
  int beg = rowptr[wid], end = rowptr[wid + 1];
  int head = lane >> 4;
  float edv = ed[wid * 4 + head];
  float ax = 0.f, ay = 0.f, z = 0.f;
  int s_next = csr[beg];              // deg >= 1 always (self-loop)
  for (int e = beg; e < end; ++e) {
    int s = s_next;
    if (e + 1 < end) s_next = csr[e + 1];
    float t = es[s * 4 + head] + edv;
    t = t > 0.f ? t : NEG_SLOPE * t;  // leaky_relu
    float w = __expf(t);              // no max-shift needed: |t| small
    float2 hv = *(const float2*)(hx + (size_t)s * 128 + 2 * lane);
    ax = fmaf(w, hv.x, ax);
    ay = fmaf(w, hv.y, ay);
    z += w;
  }
  float inv = 1.f / (z + 1e-16f);
  float vx = ax * inv, vy = ay * inv;
  if (MODE == 0) {
    vx += bias[2 * lane]; vy += bias[2 * lane + 1];
    vx = vx > 0.f ? vx : 0.f;  vy = vy > 0.f ? vy : 0.f;
    *(float2*)(outp + (size_t)wid * 128 + 2 * lane) = make_float2(vx, vy);
  } else {
    vx += __shfl_xor(vx, 16); vx += __shfl_xor(vx, 32);
    vy += __shfl_xor(vy, 16); vy += __shfl_xor(vy, 32);
    if (lane < 16) {
      float ox = vx * 0.25f + bias[2 * lane];
      float oy = vy * 0.25f + bias[2 * lane + 1];
      *(float2*)(outp + (size_t)wid * 32 + 2 * lane) = make_float2(ox, oy);
    }
  }
}

extern "C" void kernel_launch(void* const* d_in, const int* in_sizes, int n_in,
                              void* d_out, int out_size, void* d_ws, size_t ws_size,
                              hipStream_t stream) {
  const float* x   = (const float*)d_in[0];
  const int*   ei  = (const int*)d_in[1];
  const float* W1  = (const float*)d_in[2];
  const float* a1s = (const float*)d_in[3];
  const float* a1d = (const float*)d_in[4];
  const float* b1  = (const float*)d_in[5];
  const float* W2  = (const float*)d_in[6];
  const float* a2s = (const float*)d_in[7];
  const float* a2d = (const float*)d_in[8];
  const float* b2  = (const float*)d_in[9];
  const float* M1w = (const float*)d_in[10];
  const float* M1b = (const float*)d_in[11];
  const float* g1  = (const float*)d_in[12];
  const float* be1 = (const float*)d_in[13];
  const float* M2w = (const float*)d_in[14];
  const float* M2b = (const float*)d_in[15];
  const float* g2  = (const float*)d_in[16];
  const float* be2 = (const float*)d_in[17];
  const float* W3  = (const float*)d_in[18];
  const float* a3s = (const float*)d_in[19];
  const float* a3d = (const float*)d_in[20];
  const float* b3  = (const float*)d_in[21];

  const int N = in_sizes[0] / 128;
  const int E = in_sizes[1] / 2;

  char* w = (char*)d_ws;
  float* bufA = (float*)w; w += (size_t)N * 128 * 4;
  float* bufB = (float*)w; w += (size_t)N * 128 * 4;
  float* bufM = (float*)w; w += (size_t)N * 64 * 4;
  float* esb  = (float*)w; w += (size_t)N * 4 * 4;
  float* edb  = (float*)w; w += (size_t)N * 4 * 4;
  int* deg    = (int*)w;   w += (size_t)N * 4;
  int* inc    = (int*)w;   w += (size_t)N * 4;
  int* rowptr = (int*)w;   w += (size_t)(N + 1) * 4;
  int* pos    = (int*)w;   w += (size_t)N * 4;
  int* bsum   = (int*)w;   w += 256 * 4;
  int* csr    = (int*)w;   w += (size_t)(E + N) * 4;
  // split-bf16 transposed weights (hi/lo), [P][K] each
  unsigned short* W1h = (unsigned short*)w; w += 16384 * 2;
  unsigned short* W1l = (unsigned short*)w; w += 16384 * 2;
  unsigned short* W2h = (unsigned short*)w; w += 16384 * 2;
  unsigned short* W2l = (unsigned short*)w; w += 16384 * 2;
  unsigned short* W3h = (unsigned short*)w; w += 16384 * 2;
  unsigned short* W3l = (unsigned short*)w; w += 16384 * 2;
  unsigned short* M1h = (unsigned short*)w; w += 8192 * 2;
  unsigned short* M1l = (unsigned short*)w; w += 8192 * 2;
  unsigned short* M2h = (unsigned short*)w; w += 8192 * 2;
  unsigned short* M2l = (unsigned short*)w; w += 8192 * 2;

  const int nb = (N + 255) / 256;
  const int eb = (E + 255) / 256;
  const int gb = (N + 127) / 128;
  const int ab = (N * 4 + 255) / 256;
  const int aggb = (N + 3) / 4;   // 4 waves per block

  // ---- weight prep (independent of everything else) ----
  wprep<<<64, 256, 0, stream>>>(W1, W1h, W1l, 128, 7);
  wprep<<<64, 256, 0, stream>>>(W2, W2h, W2l, 128, 7);
  wprep<<<64, 256, 0, stream>>>(W3, W3h, W3l, 128, 7);
  wprep<<<32, 256, 0, stream>>>(M1w, M1h, M1l, 128, 6);  // [128][64] -> [64][128]
  wprep<<<32, 256, 0, stream>>>(M2w, M2h, M2l, 64, 7);   // [64][128] -> [128][64]

  // ---- CSR build (counting sort by dst) ----
  deg_init<<<nb, 256, 0, stream>>>(deg, N);
  deg_count<<<eb, 256, 0, stream>>>(ei, deg, E);
  scan1<<<nb, 256, 0, stream>>>(deg, inc, bsum, N);
  scan2<<<1, 256, 0, stream>>>(bsum, nb);
  scan3<<<nb, 256, 0, stream>>>(inc, deg, bsum, rowptr, pos, N);
  scatter_e<<<eb, 256, 0, stream>>>(ei, pos, csr, E);
  scatter_l<<<nb, 256, 0, stream>>>(pos, csr, N);

  // ---- layer 0: conv0 -> relu -> MLP(bn(relu(.))) x2 ----
  gemm_mfma<128, 128, 0><<<gb, 256, 0, stream>>>(x, W1h, W1l, bufA, N, nullptr, nullptr, nullptr);
  attn_scores<<<ab, 256, 0, stream>>>(bufA, a1s, a1d, esb, edb, N);
  gat_agg<0><<<aggb, 256, 0, stream>>>(bufA, rowptr, csr, esb, edb, b1, bufB, N);
  gemm_mfma<64, 128, 1><<<gb, 256, 0, stream>>>(bufB, M1h, M1l, bufM, N, M1b, g1, be1);
  gemm_mfma<128, 64, 1><<<gb, 256, 0, stream>>>(bufM, M2h, M2l, bufA, N, M2b, g2, be2);

  // ---- layer 1: conv1 -> relu ----
  gemm_mfma<128, 128, 0><<<gb, 256, 0, stream>>>(bufA, W2h, W2l, bufB, N, nullptr, nullptr, nullptr);
  attn_scores<<<ab, 256, 0, stream>>>(bufB, a2s, a2d, esb, edb, N);
  gat_agg<0><<<aggb, 256, 0, stream>>>(bufB, rowptr, csr, esb, edb, b2, bufA, N);

  // ---- layer 2: conv2, mean over heads, +b3 (no relu) ----
  gemm_mfma<128, 128, 0><<<gb, 256, 0, stream>>>(bufA, W3h, W3l, bufB, N, nullptr, nullptr, nullptr);
  attn_scores<<<ab, 256, 0, stream>>>(bufB, a3s, a3d, esb, edb, N);
  gat_agg<1><<<aggb, 256, 0, stream>>>(bufB, rowptr, csr, esb, edb, b3, (float*)d_out, N);
}

// Round 4
// 515.261 us; speedup vs baseline: 1.1223x; 1.0763x over previous
//
#include <hip/hip_runtime.h>
#include <hip/hip_bf16.h>

#define NEG_SLOPE 0.2f
#define BN_RS 0.9999950000374997f   // 1/sqrt(1 + 1e-5)

typedef __attribute__((ext_vector_type(8))) short short8;   // 8 bf16 (4 VGPR)
typedef __attribute__((ext_vector_type(4))) float f32x4;    // MFMA acc

// split fp32 -> bf16 hi (RNE) + bf16 lo (RNE of residual)
__device__ __forceinline__ void split_bf16(float f, unsigned short& h, unsigned short& l) {
  union { float f; unsigned u; } c; c.f = f;
  unsigned r = c.u + 0x7FFF + ((c.u >> 16) & 1);
  h = (unsigned short)(r >> 16);
  union { unsigned u; float f; } hv; hv.u = ((unsigned)h) << 16;
  float lf = f - hv.f;
  union { float f; unsigned u; } lc; lc.f = lf;
  unsigned rl = lc.u + 0x7FFF + ((lc.u >> 16) & 1);
  l = (unsigned short)(rl >> 16);
}

// ---------------- CSR build ----------------

__global__ void deg_init(int* deg, int N) {
  int i = blockIdx.x * 256 + threadIdx.x;
  if (i < N) deg[i] = 1;             // self-loop
}
__global__ void deg_count(const int* __restrict__ ei, int* deg, int E) {
  int i = blockIdx.x * 256 + threadIdx.x;
  if (i < E) atomicAdd(&deg[ei[E + i]], 1);
}
__global__ void scan1(const int* __restrict__ deg, int* __restrict__ inc,
                      int* __restrict__ bsum, int N) {
  __shared__ int sd[256];
  int tid = threadIdx.x;
  int i = blockIdx.x * 256 + tid;
  int v = (i < N) ? deg[i] : 0;
  sd[tid] = v;
  __syncthreads();
  for (int off = 1; off < 256; off <<= 1) {
    int t = (tid >= off) ? sd[tid - off] : 0;
    __syncthreads();
    sd[tid] += t;
    __syncthreads();
  }
  if (i < N) inc[i] = sd[tid];
  if (tid == 255) bsum[blockIdx.x] = sd[255];
}
__global__ void scan2(int* bsum, int nb) {  // nb <= 256
  __shared__ int sd[256];
  int tid = threadIdx.x;
  int v = (tid < nb) ? bsum[tid] : 0;
  sd[tid] = v;
  __syncthreads();
  for (int off = 1; off < 256; off <<= 1) {
    int t = (tid >= off) ? sd[tid - off] : 0;
    __syncthreads();
    sd[tid] += t;
    __syncthreads();
  }
  if (tid < nb) bsum[tid] = sd[tid] - v;   // exclusive
}
__global__ void scan3(const int* __restrict__ inc, const int* __restrict__ deg,
                      const int* __restrict__ bsum, int* __restrict__ rowptr,
                      int* __restrict__ pos, int N) {
  int i = blockIdx.x * 256 + threadIdx.x;
  if (i < N) {
    int r = inc[i] + bsum[blockIdx.x];
    rowptr[i + 1] = r;
    pos[i] = r - deg[i];
    if (i == 0) rowptr[0] = 0;
  }
}
__global__ void scatter_e(const int* __restrict__ ei, int* pos,
                          int* __restrict__ csr, int E) {
  int i = blockIdx.x * 256 + threadIdx.x;
  if (i < E) {
    int s = ei[i], d = ei[E + i];
    int p = atomicAdd(&pos[d], 1);
    csr[p] = s;
  }
}
__global__ void scatter_l(int* pos, int* __restrict__ csr, int N) {
  int i = blockIdx.x * 256 + threadIdx.x;
  if (i < N) {
    int p = atomicAdd(&pos[i], 1);
    csr[p] = i;
  }
}

// ---------------- weight prep (all 5 matrices, one dispatch) ----------------
// W[K][P] fp32 -> transposed split-bf16 hi/lo [P][K]
__global__ void wprep_all(
    const float* __restrict__ W1, unsigned short* __restrict__ W1h, unsigned short* __restrict__ W1l,
    const float* __restrict__ W2, unsigned short* __restrict__ W2h, unsigned short* __restrict__ W2l,
    const float* __restrict__ W3, unsigned short* __restrict__ W3h, unsigned short* __restrict__ W3l,
    const float* __restrict__ M1, unsigned short* __restrict__ M1h, unsigned short* __restrict__ M1l,
    const float* __restrict__ M2, unsigned short* __restrict__ M2h, unsigned short* __restrict__ M2l) {
  int b = blockIdx.x;
  const float* W; unsigned short* H; unsigned short* L;
  int K, pshift, base;
  if (b < 64)       { W = W1; H = W1h; L = W1l; K = 128; pshift = 7; base = 0;   }
  else if (b < 128) { W = W2; H = W2h; L = W2l; K = 128; pshift = 7; base = 64;  }
  else if (b < 192) { W = W3; H = W3h; L = W3l; K = 128; pshift = 7; base = 128; }
  else if (b < 224) { W = M1; H = M1h; L = M1l; K = 128; pshift = 6; base = 192; }
  else              { W = M2; H = M2h; L = M2l; K = 64;  pshift = 7; base = 224; }
  int i = (b - base) * 256 + threadIdx.x;     // i = k*P + p
  int k = i >> pshift;
  int p = i & ((1 << pshift) - 1);
  unsigned short h, l;
  split_bf16(W[i], h, l);
  H[(size_t)p * K + k] = h;
  L[(size_t)p * K + k] = l;
}

// ---------------- GEMM via split-bf16 MFMA ----------------
// C[N x P] = A[N x K] @ W[K x P];  A fp32, W pre-split bf16 hi/lo transposed [P][K].
// D = Ah@Wh + Ah@Wl + Al@Wh  (single accumulator) -> fp32-class accuracy.
// EPI 0: plain store. EPI 1: bn(relu(acc + bias)).
template <int P, int K, int EPI>
__global__ __launch_bounds__(256) void gemm_mfma(
    const float* __restrict__ A, const unsigned short* __restrict__ WtH,
    const unsigned short* __restrict__ WtL, float* __restrict__ C, int N,
    const float* __restrict__ bias, const float* __restrict__ gamma,
    const float* __restrict__ beta) {
  constexpr int CT = P / 64;      // col-tiles (of 16) per wave
  constexpr int KT = K / 32;      // k-tiles
  __shared__ unsigned short AsH[128][40];   // stride 40 ushorts = 80 B (16B-aligned rows)
  __shared__ unsigned short AsL[128][40];
  __shared__ unsigned short WsH[P][40];
  __shared__ unsigned short WsL[P][40];
  const int tid = threadIdx.x;
  const int wave = tid >> 6;
  const int lane = tid & 63;
  const int quad = lane >> 4;
  const int l16 = lane & 15;
  const int row0 = blockIdx.x * 128;

  f32x4 acc[8][CT];
#pragma unroll
  for (int rt = 0; rt < 8; rt++)
#pragma unroll
    for (int ct = 0; ct < CT; ct++) acc[rt][ct] = (f32x4){0.f, 0.f, 0.f, 0.f};

  for (int kc = 0; kc < KT; ++kc) {
    // ---- stage A tile (128 x 32 fp32 -> split bf16), coalesced float4 loads ----
#pragma unroll
    for (int it = 0; it < 4; ++it) {
      int idx = it * 256 + tid;          // 1024 float4s
      int r = idx >> 3;
      int c4 = (idx & 7) * 4;
      int gr = row0 + r;
      float4 v;
      if (gr < N) v = *(const float4*)(A + (size_t)gr * K + kc * 32 + c4);
      else v = make_float4(0.f, 0.f, 0.f, 0.f);
      unsigned short h0,h1,h2,h3,l0,l1,l2,l3;
      split_bf16(v.x, h0, l0); split_bf16(v.y, h1, l1);
      split_bf16(v.z, h2, l2); split_bf16(v.w, h3, l3);
      *(ushort4*)&AsH[r][c4] = make_ushort4(h0, h1, h2, h3);
      *(ushort4*)&AsL[r][c4] = make_ushort4(l0, l1, l2, l3);
    }
    // ---- stage W tile (P x 32 bf16 hi/lo), contiguous ushort8 loads ----
#pragma unroll
    for (int it = 0; it < P / 64; ++it) {
      int idx = it * 256 + tid;          // P*4 ushort8 chunks
      int p = idx >> 2;
      int c8 = (idx & 3) * 8;
      short8 vh = *(const short8*)(WtH + (size_t)p * K + kc * 32 + c8);
      short8 vl = *(const short8*)(WtL + (size_t)p * K + kc * 32 + c8);
      *(short8*)&WsH[p][c8] = vh;
      *(short8*)&WsL[p][c8] = vl;
    }
    __syncthreads();

    // ---- B fragments for this k-tile ----
    short8 bh[CT], bl[CT];
#pragma unroll
    for (int ct = 0; ct < CT; ++ct) {
      int n = wave * (16 * CT) + ct * 16 + l16;
      bh[ct] = *(const short8*)&WsH[n][quad * 8];
      bl[ct] = *(const short8*)&WsL[n][quad * 8];
    }
    // ---- MFMA over 8 row-tiles ----
#pragma unroll
    for (int rt = 0; rt < 8; ++rt) {
      int m = rt * 16 + l16;
      short8 ah = *(const short8*)&AsH[m][quad * 8];
      short8 al = *(const short8*)&AsL[m][quad * 8];
#pragma unroll
      for (int ct = 0; ct < CT; ++ct) {
        acc[rt][ct] = __builtin_amdgcn_mfma_f32_16x16x32_bf16(ah, bh[ct], acc[rt][ct], 0, 0, 0);
        acc[rt][ct] = __builtin_amdgcn_mfma_f32_16x16x32_bf16(al, bh[ct], acc[rt][ct], 0, 0, 0);
        acc[rt][ct] = __builtin_amdgcn_mfma_f32_16x16x32_bf16(ah, bl[ct], acc[rt][ct], 0, 0, 0);
      }
    }
    __syncthreads();
  }

  // ---- epilogue: C/D layout col=lane&15, row=quad*4+reg ----
#pragma unroll
  for (int ct = 0; ct < CT; ++ct) {
    int c = wave * (16 * CT) + ct * 16 + l16;
    float bi = 0.f, ga = 0.f, be = 0.f;
    if (EPI == 1) { bi = bias[c]; ga = gamma[c] * BN_RS; be = beta[c]; }
#pragma unroll
    for (int rt = 0; rt < 8; ++rt) {
#pragma unroll
      for (int g = 0; g < 4; ++g) {
        int r = row0 + rt * 16 + quad * 4 + g;
        if (r < N) {
          float v = acc[rt][ct][g];
          if (EPI == 1) {
            v += bi;
            v = v > 0.f ? v : 0.f;
            v = v * ga + be;
          }
          C[(size_t)r * P + c] = v;
        }
      }
    }
  }
}

// ---------------- attention scores: es/ed[n][h] = <h_row, a_s/a_d> ----------------
__global__ __launch_bounds__(256) void attn_scores(
    const float* __restrict__ hx, const float* __restrict__ as_,
    const float* __restrict__ ad_, float* __restrict__ es, float* __restrict__ ed,
    int N) {
  int t = blockIdx.x * 256 + threadIdx.x;   // n*4 + h
  if (t >= N * 4) return;
  int h = t & 3;
  const float* row = hx + (size_t)(t >> 2) * 128 + h * 32;
  float s = 0.f, d = 0.f;
#pragma unroll
  for (int q = 0; q < 8; q++) {
    float4 hv = *(const float4*)(row + 4 * q);
    float4 ua = *(const float4*)(as_ + h * 32 + 4 * q);
    float4 ud = *(const float4*)(ad_ + h * 32 + 4 * q);
    s += hv.x*ua.x + hv.y*ua.y + hv.z*ua.z + hv.w*ua.w;
    d += hv.x*ud.x + hv.y*ud.y + hv.z*ud.z + hv.w*ud.w;
  }
  es[t] = s; ed[t] = d;
}

// ---------------- GAT aggregation: one wave per dst node, 4-wide pipelined ----------------
// lane i holds features (2i, 2i+1); head = i>>4. All 16 lanes of a head group
// compute identical w and z, so normalization needs no reduction.
// MODE 0: out fp32 [N,128] = relu(S/z + bias)  (concat)
// MODE 1: out fp32 [N,32]  = mean_heads(S/z) + bias  (no relu)
template <int MODE>
__global__ __launch_bounds__(256) void gat_agg(
    const float* __restrict__ hx, const int* __restrict__ rowptr,
    const int* __restrict__ csr, const float* __restrict__ es,
    const float* __restrict__ ed, const float* __restrict__ bias,
    float* __restrict__ outp, int N) {
  int wid = (blockIdx.x * 256 + threadIdx.x) >> 6;
  if (wid >= N) return;
  int lane = threadIdx.x & 63;
  int beg = rowptr[wid], end = rowptr[wid + 1];
  int head = lane >> 4;
  float edv = ed[wid * 4 + head];
  float ax = 0.f, ay = 0.f, z = 0.f;
  int e = beg;
  // 4-wide: batch the two dependent latency levels (csr -> es/hv)
  for (; e + 4 <= end; e += 4) {
    int s0 = csr[e], s1 = csr[e + 1], s2 = csr[e + 2], s3 = csr[e + 3];
    float t0 = es[s0 * 4 + head], t1 = es[s1 * 4 + head];
    float t2 = es[s2 * 4 + head], t3 = es[s3 * 4 + head];
    float2 h0 = *(const float2*)(hx + (size_t)s0 * 128 + 2 * lane);
    float2 h1 = *(const float2*)(hx + (size_t)s1 * 128 + 2 * lane);
    float2 h2 = *(const float2*)(hx + (size_t)s2 * 128 + 2 * lane);
    float2 h3 = *(const float2*)(hx + (size_t)s3 * 128 + 2 * lane);
    t0 += edv; t1 += edv; t2 += edv; t3 += edv;
    t0 = t0 > 0.f ? t0 : NEG_SLOPE * t0;
    t1 = t1 > 0.f ? t1 : NEG_SLOPE * t1;
    t2 = t2 > 0.f ? t2 : NEG_SLOPE * t2;
    t3 = t3 > 0.f ? t3 : NEG_SLOPE * t3;
    float w0 = __expf(t0), w1 = __expf(t1), w2 = __expf(t2), w3 = __expf(t3);
    z += (w0 + w1) + (w2 + w3);
    ax = fmaf(w0, h0.x, ax); ay = fmaf(w0, h0.y, ay);
    ax = fmaf(w1, h1.x, ax); ay = fmaf(w1, h1.y, ay);
    ax = fmaf(w2, h2.x, ax); ay = fmaf(w2, h2.y, ay);
    ax = fmaf(w3, h3.x, ax); ay = fmaf(w3, h3.y, ay);
  }
  for (; e < end; ++e) {
    int s = csr[e];
    float t = es[s * 4 + head] + edv;
    t = t > 0.f ? t : NEG_SLOPE * t;
    float w = __expf(t);
    float2 hv = *(const float2*)(hx + (size_t)s * 128 + 2 * lane);
    ax = fmaf(w, hv.x, ax);
    ay = fmaf(w, hv.y, ay);
    z += w;
  }
  float inv = 1.f / (z + 1e-16f);
  float vx = ax * inv, vy = ay * inv;
  if (MODE == 0) {
    vx += bias[2 * lane]; vy += bias[2 * lane + 1];
    vx = vx > 0.f ? vx : 0.f;  vy = vy > 0.f ? vy : 0.f;
    *(float2*)(outp + (size_t)wid * 128 + 2 * lane) = make_float2(vx, vy);
  } else {
    vx += __shfl_xor(vx, 16); vx += __shfl_xor(vx, 32);
    vy += __shfl_xor(vy, 16); vy += __shfl_xor(vy, 32);
    if (lane < 16) {
      float ox = vx * 0.25f + bias[2 * lane];
      float oy = vy * 0.25f + bias[2 * lane + 1];
      *(float2*)(outp + (size_t)wid * 32 + 2 * lane) = make_float2(ox, oy);
    }
  }
}

extern "C" void kernel_launch(void* const* d_in, const int* in_sizes, int n_in,
                              void* d_out, int out_size, void* d_ws, size_t ws_size,
                              hipStream_t stream) {
  const float* x   = (const float*)d_in[0];
  const int*   ei  = (const int*)d_in[1];
  const float* W1  = (const float*)d_in[2];
  const float* a1s = (const float*)d_in[3];
  const float* a1d = (const float*)d_in[4];
  const float* b1  = (const float*)d_in[5];
  const float* W2  = (const float*)d_in[6];
  const float* a2s = (const float*)d_in[7];
  const float* a2d = (const float*)d_in[8];
  const float* b2  = (const float*)d_in[9];
  const float* M1w = (const float*)d_in[10];
  const float* M1b = (const float*)d_in[11];
  const float* g1  = (const float*)d_in[12];
  const float* be1 = (const float*)d_in[13];
  const float* M2w = (const float*)d_in[14];
  const float* M2b = (const float*)d_in[15];
  const float* g2  = (const float*)d_in[16];
  const float* be2 = (const float*)d_in[17];
  const float* W3  = (const float*)d_in[18];
  const float* a3s = (const float*)d_in[19];
  const float* a3d = (const float*)d_in[20];
  const float* b3  = (const float*)d_in[21];

  const int N = in_sizes[0] / 128;
  const int E = in_sizes[1] / 2;

  char* w = (char*)d_ws;
  float* bufA = (float*)w; w += (size_t)N * 128 * 4;
  float* bufB = (float*)w; w += (size_t)N * 128 * 4;
  float* bufM = (float*)w; w += (size_t)N * 64 * 4;
  float* esb  = (float*)w; w += (size_t)N * 4 * 4;
  float* edb  = (float*)w; w += (size_t)N * 4 * 4;
  int* deg    = (int*)w;   w += (size_t)N * 4;
  int* inc    = (int*)w;   w += (size_t)N * 4;
  int* rowptr = (int*)w;   w += (size_t)(N + 1) * 4;
  int* pos    = (int*)w;   w += (size_t)N * 4;
  int* bsum   = (int*)w;   w += 256 * 4;
  int* csr    = (int*)w;   w += (size_t)(E + N) * 4;
  // split-bf16 transposed weights (hi/lo), [P][K] each
  unsigned short* W1h = (unsigned short*)w; w += 16384 * 2;
  unsigned short* W1l = (unsigned short*)w; w += 16384 * 2;
  unsigned short* W2h = (unsigned short*)w; w += 16384 * 2;
  unsigned short* W2l = (unsigned short*)w; w += 16384 * 2;
  unsigned short* W3h = (unsigned short*)w; w += 16384 * 2;
  unsigned short* W3l = (unsigned short*)w; w += 16384 * 2;
  unsigned short* M1h = (unsigned short*)w; w += 8192 * 2;
  unsigned short* M1l = (unsigned short*)w; w += 8192 * 2;
  unsigned short* M2h = (unsigned short*)w; w += 8192 * 2;
  unsigned short* M2l = (unsigned short*)w; w += 8192 * 2;

  const int nb = (N + 255) / 256;
  const int eb = (E + 255) / 256;
  const int gb = (N + 127) / 128;
  const int ab = (N * 4 + 255) / 256;
  const int aggb = (N + 3) / 4;   // 4 waves per block

  // ---- weight prep (single dispatch) ----
  wprep_all<<<256, 256, 0, stream>>>(W1, W1h, W1l, W2, W2h, W2l, W3, W3h, W3l,
                                     M1w, M1h, M1l, M2w, M2h, M2l);

  // ---- CSR build (counting sort by dst) ----
  deg_init<<<nb, 256, 0, stream>>>(deg, N);
  deg_count<<<eb, 256, 0, stream>>>(ei, deg, E);
  scan1<<<nb, 256, 0, stream>>>(deg, inc, bsum, N);
  scan2<<<1, 256, 0, stream>>>(bsum, nb);
  scan3<<<nb, 256, 0, stream>>>(inc, deg, bsum, rowptr, pos, N);
  scatter_e<<<eb, 256, 0, stream>>>(ei, pos, csr, E);
  scatter_l<<<nb, 256, 0, stream>>>(pos, csr, N);

  // ---- layer 0: conv0 -> relu -> MLP(bn(relu(.))) x2 ----
  gemm_mfma<128, 128, 0><<<gb, 256, 0, stream>>>(x, W1h, W1l, bufA, N, nullptr, nullptr, nullptr);
  attn_scores<<<ab, 256, 0, stream>>>(bufA, a1s, a1d, esb, edb, N);
  gat_agg<0><<<aggb, 256, 0, stream>>>(bufA, rowptr, csr, esb, edb, b1, bufB, N);
  gemm_mfma<64, 128, 1><<<gb, 256, 0, stream>>>(bufB, M1h, M1l, bufM, N, M1b, g1, be1);
  gemm_mfma<128, 64, 1><<<gb, 256, 0, stream>>>(bufM, M2h, M2l, bufA, N, M2b, g2, be2);

  // ---- layer 1: conv1 -> relu ----
  gemm_mfma<128, 128, 0><<<gb, 256, 0, stream>>>(bufA, W2h, W2l, bufB, N, nullptr, nullptr, nullptr);
  attn_scores<<<ab, 256, 0, stream>>>(bufB, a2s, a2d, esb, edb, N);
  gat_agg<0><<<aggb, 256, 0, stream>>>(bufB, rowptr, csr, esb, edb, b2, bufA, N);

  // ---- layer 2: conv2, mean over heads, +b3 (no relu) ----
  gemm_mfma<128, 128, 0><<<gb, 256, 0, stream>>>(bufA, W3h, W3l, bufB, N, nullptr, nullptr, nullptr);
  attn_scores<<<ab, 256, 0, stream>>>(bufB, a3s, a3d, esb, edb, N);
  gat_agg<1><<<aggb, 256, 0, stream>>>(bufB, rowptr, csr, esb, edb, b3, (float*)d_out, N);
}

// Round 5
// 415.536 us; speedup vs baseline: 1.3916x; 1.2400x over previous
//
#include <hip/hip_runtime.h>
#include <hip/hip_bf16.h>

#define NEG_SLOPE 0.2f
#define BN_RS 0.9999950000374997f   // 1/sqrt(1 + 1e-5)

typedef __attribute__((ext_vector_type(8))) _Float16 f16x8;  // MFMA A/B frag (4 VGPR)
typedef __attribute__((ext_vector_type(2))) _Float16 f16x2;
typedef __attribute__((ext_vector_type(4))) float f32x4;     // MFMA acc

// split fp32 -> fp16 hi (RNE) + fp16 lo (RNE of residual); hi+lo carries ~22 bits
__device__ __forceinline__ void store_split(float w, _Float16* H, _Float16* L, size_t off) {
  _Float16 h = (_Float16)w;
  H[off] = h;
  L[off] = (_Float16)(w - (float)h);
}

// ---------------- CSR build ----------------

__global__ void deg_init(int* deg, int N) {
  int i = blockIdx.x * 256 + threadIdx.x;
  if (i < N) deg[i] = 1;             // self-loop
}
__global__ void deg_count(const int* __restrict__ ei, int* deg, int E) {
  int i = blockIdx.x * 256 + threadIdx.x;
  if (i < E) atomicAdd(&deg[ei[E + i]], 1);
}
__global__ void scan1(const int* __restrict__ deg, int* __restrict__ inc,
                      int* __restrict__ bsum, int N) {
  __shared__ int sd[256];
  int tid = threadIdx.x;
  int i = blockIdx.x * 256 + tid;
  int v = (i < N) ? deg[i] : 0;
  sd[tid] = v;
  __syncthreads();
  for (int off = 1; off < 256; off <<= 1) {
    int t = (tid >= off) ? sd[tid - off] : 0;
    __syncthreads();
    sd[tid] += t;
    __syncthreads();
  }
  if (i < N) inc[i] = sd[tid];
  if (tid == 255) bsum[blockIdx.x] = sd[255];
}
__global__ void scan2(int* bsum, int nb) {  // nb <= 256
  __shared__ int sd[256];
  int tid = threadIdx.x;
  int v = (tid < nb) ? bsum[tid] : 0;
  sd[tid] = v;
  __syncthreads();
  for (int off = 1; off < 256; off <<= 1) {
    int t = (tid >= off) ? sd[tid - off] : 0;
    __syncthreads();
    sd[tid] += t;
    __syncthreads();
  }
  if (tid < nb) bsum[tid] = sd[tid] - v;   // exclusive
}
// rowptr + edge-scatter start + self-loop write (self-loop slot = rowptr[i+1]-1)
__global__ void scan3(const int* __restrict__ inc, const int* __restrict__ deg,
                      const int* __restrict__ bsum, int* __restrict__ rowptr,
                      int* __restrict__ pos, int* __restrict__ csr, int N) {
  int i = blockIdx.x * 256 + threadIdx.x;
  if (i < N) {
    int r = inc[i] + bsum[blockIdx.x];
    rowptr[i + 1] = r;
    pos[i] = r - deg[i];
    csr[r - 1] = i;
    if (i == 0) rowptr[0] = 0;
  }
}
__global__ void scatter_e(const int* __restrict__ ei, int* pos,
                          int* __restrict__ csr, int E) {
  int i = blockIdx.x * 256 + threadIdx.x;
  if (i < E) {
    int s = ei[i], d = ei[E + i];
    int p = atomicAdd(&pos[d], 1);
    csr[p] = s;
  }
}

// ---------------- weight prep ----------------
// conv W[128][128] -> Wt hi/lo fp16 [144][128]: rows 0..127 = W^T split,
// rows 128..131 = combined attn-src cols (es = A @ ws), 132..135 attn-dst, 136..143 zero.
// M1 [128][64] -> [64][128]; M2 [64][128] -> [128][64].
__device__ __forceinline__ void wprep_conv(const float* __restrict__ W,
                                           const float* __restrict__ as_,
                                           const float* __restrict__ ad_,
                                           _Float16* __restrict__ H, _Float16* __restrict__ L,
                                           int lb, int tid) {
  if (lb < 64) {                       // transpose region
    int idx = lb * 256 + tid;
    int k = idx >> 7, p = idx & 127;
    store_split(W[k * 128 + p], H, L, (size_t)p * 128 + k);
  } else if (lb < 68) {                // attn-combined rows
    int idx = (lb - 64) * 256 + tid;   // 1024 entries: 8 rows x 128 k
    int rl = idx >> 7, k = idx & 127;
    const float* a = (rl < 4) ? as_ : ad_;
    int h = rl & 3;
    float s = 0.f;
#pragma unroll
    for (int f = 0; f < 32; f++) s += W[k * 128 + h * 32 + f] * a[h * 32 + f];
    store_split(s, H, L, (size_t)(128 + rl) * 128 + k);
  } else {                             // zero pad rows 136..143
    int idx = (lb - 68) * 256 + tid;
    int rl = idx >> 7, k = idx & 127;
    H[(size_t)(136 + rl) * 128 + k] = (_Float16)0.f;
    L[(size_t)(136 + rl) * 128 + k] = (_Float16)0.f;
  }
}

__global__ void wprep_all(
    const float* __restrict__ W1, const float* __restrict__ a1s, const float* __restrict__ a1d,
    _Float16* __restrict__ W1H, _Float16* __restrict__ W1L,
    const float* __restrict__ W2, const float* __restrict__ a2s, const float* __restrict__ a2d,
    _Float16* __restrict__ W2H, _Float16* __restrict__ W2L,
    const float* __restrict__ W3, const float* __restrict__ a3s, const float* __restrict__ a3d,
    _Float16* __restrict__ W3H, _Float16* __restrict__ W3L,
    const float* __restrict__ M1, _Float16* __restrict__ M1H, _Float16* __restrict__ M1L,
    const float* __restrict__ M2, _Float16* __restrict__ M2H, _Float16* __restrict__ M2L) {
  int b = blockIdx.x, tid = threadIdx.x;
  if (b < 72)       wprep_conv(W1, a1s, a1d, W1H, W1L, b, tid);
  else if (b < 144) wprep_conv(W2, a2s, a2d, W2H, W2L, b - 72, tid);
  else if (b < 216) wprep_conv(W3, a3s, a3d, W3H, W3L, b - 144, tid);
  else if (b < 248) {                  // M1: [128][64] -> [64][128]
    int idx = (b - 216) * 256 + tid;
    int k = idx >> 6, p = idx & 63;
    store_split(M1[k * 64 + p], M1H, M1L, (size_t)p * 128 + k);
  } else {                             // M2: [64][128] -> [128][64]
    int idx = (b - 248) * 256 + tid;
    int k = idx >> 7, p = idx & 127;
    store_split(M2[k * 128 + p], M2H, M2L, (size_t)p * 64 + k);
  }
}

// ---------------- GEMM via fp16 MFMA, W split hi/lo ----------------
// C[N x PST](fp16) = A[N x K] @ W; A fp16 (or fp32 for layer 0, cvt in staging).
// D = A@Wh + A@Wl. AUG=1: PT=PST+16, extra tile -> es/ed fp32 (attn scores fused).
// EPI 0: raw store. EPI 1: bn(relu(acc + bias)).
template <int PT, int PST, int K, int EPI, int AUG, typename TA>
__global__ __launch_bounds__(256) void gemm_f16(
    const TA* __restrict__ A, const _Float16* __restrict__ WtH,
    const _Float16* __restrict__ WtL, _Float16* __restrict__ C, int N,
    const float* __restrict__ bias, const float* __restrict__ gamma,
    const float* __restrict__ beta, float* __restrict__ esb,
    float* __restrict__ edb) {
  constexpr int NTILE = PT / 16;
  constexpr int CTB = NTILE / 4;      // base col-tiles per wave
  constexpr int REM = NTILE % 4;      // 0 or 1 (extra tile on wave 0)
  constexpr int KT = K / 32;
  __shared__ _Float16 As[128 * 32];
  __shared__ _Float16 WsH[PT * 32];
  __shared__ _Float16 WsL[PT * 32];
  const int tid = threadIdx.x;
  const int wave = tid >> 6, lane = tid & 63;
  const int quad = lane >> 4, l16 = lane & 15;
  const int row0 = blockIdx.x * 128;
  const bool xw = (REM != 0) && (wave == 0);

  f32x4 acc[8][CTB + (REM ? 1 : 0)];
#pragma unroll
  for (int rt = 0; rt < 8; rt++)
#pragma unroll
    for (int nt = 0; nt < CTB + (REM ? 1 : 0); nt++) acc[rt][nt] = (f32x4){0.f, 0.f, 0.f, 0.f};

  for (int kc = 0; kc < KT; ++kc) {
    // ---- stage A: 128 rows x 32 halves ----
    {
      int r = tid >> 1, part = tid & 1;
      int gr = row0 + r;
      _Float16* dst = &As[r * 32 + part * 16];
      if (gr < N) {
        const TA* src = A + (size_t)gr * K + kc * 32 + part * 16;
        if constexpr (sizeof(TA) == 4) {     // fp32 input (layer 0): cvt
          f16x8 h0, h1;
#pragma unroll
          for (int j = 0; j < 8; j++) { h0[j] = (_Float16)src[j]; h1[j] = (_Float16)src[8 + j]; }
          *(f16x8*)dst = h0; *(f16x8*)(dst + 8) = h1;
        } else {                              // fp16: raw copy
          uint4 v0 = *(const uint4*)src;
          uint4 v1 = *(const uint4*)(src + 8);
          *(uint4*)dst = v0; *(uint4*)(dst + 8) = v1;
        }
      } else {
        *(uint4*)dst = make_uint4(0, 0, 0, 0);
        *(uint4*)(dst + 8) = make_uint4(0, 0, 0, 0);
      }
    }
    // ---- stage W hi/lo: PT rows x 32 halves each ----
    for (int idx = tid; idx < PT * 2; idx += 256) {
      int isL = idx >= PT;
      int p = isL ? idx - PT : idx;
      const _Float16* src = (isL ? WtL : WtH) + (size_t)p * K + kc * 32;
      _Float16* dst = (isL ? WsL : WsH) + p * 32;
      uint4 a0 = *(const uint4*)src;       uint4 a1 = *(const uint4*)(src + 8);
      uint4 a2 = *(const uint4*)(src + 16); uint4 a3 = *(const uint4*)(src + 24);
      *(uint4*)dst = a0; *(uint4*)(dst + 8) = a1;
      *(uint4*)(dst + 16) = a2; *(uint4*)(dst + 24) = a3;
    }
    __syncthreads();

    f16x8 bh[CTB], bl[CTB], bhE, blE;
#pragma unroll
    for (int nt = 0; nt < CTB; nt++) {
      int p = (wave * CTB + nt) * 16 + l16;
      bh[nt] = *(f16x8*)&WsH[p * 32 + quad * 8];
      bl[nt] = *(f16x8*)&WsL[p * 32 + quad * 8];
    }
    if constexpr (REM) {
      if (xw) {
        int p = 4 * CTB * 16 + l16;
        bhE = *(f16x8*)&WsH[p * 32 + quad * 8];
        blE = *(f16x8*)&WsL[p * 32 + quad * 8];
      }
    }
#pragma unroll
    for (int rt = 0; rt < 8; rt++) {
      f16x8 a = *(f16x8*)&As[(rt * 16 + l16) * 32 + quad * 8];
#pragma unroll
      for (int nt = 0; nt < CTB; nt++) {
        acc[rt][nt] = __builtin_amdgcn_mfma_f32_16x16x32_f16(a, bh[nt], acc[rt][nt], 0, 0, 0);
        acc[rt][nt] = __builtin_amdgcn_mfma_f32_16x16x32_f16(a, bl[nt], acc[rt][nt], 0, 0, 0);
      }
      if constexpr (REM) {
        if (xw) {
          acc[rt][CTB] = __builtin_amdgcn_mfma_f32_16x16x32_f16(a, bhE, acc[rt][CTB], 0, 0, 0);
          acc[rt][CTB] = __builtin_amdgcn_mfma_f32_16x16x32_f16(a, blE, acc[rt][CTB], 0, 0, 0);
        }
      }
    }
    __syncthreads();
  }

  // ---- epilogue (C/D layout: col=lane&15, row=quad*4+reg) ----
#pragma unroll
  for (int nt = 0; nt < CTB; nt++) {
    int c = (wave * CTB + nt) * 16 + l16;
    float bi = 0.f, ga = 0.f, be = 0.f;
    if constexpr (EPI == 1) { bi = bias[c]; ga = gamma[c] * BN_RS; be = beta[c]; }
#pragma unroll
    for (int rt = 0; rt < 8; rt++)
#pragma unroll
      for (int g = 0; g < 4; g++) {
        int r = row0 + rt * 16 + quad * 4 + g;
        if (r < N) {
          float v = acc[rt][nt][g];
          if constexpr (EPI == 1) { v += bi; v = v > 0.f ? v : 0.f; v = v * ga + be; }
          C[(size_t)r * PST + c] = (_Float16)v;
        }
      }
  }
  if constexpr (REM) {
    if (wave == 0 && l16 < 8) {
      float* dstb = (l16 < 4) ? esb : edb;
      int h = l16 & 3;
#pragma unroll
      for (int rt = 0; rt < 8; rt++)
#pragma unroll
        for (int g = 0; g < 4; g++) {
          int r = row0 + rt * 16 + quad * 4 + g;
          if (r < N) dstb[(size_t)r * 4 + h] = acc[rt][CTB][g];
        }
    }
  }
}

// ---------------- GAT aggregation: one wave per dst node, fp16 h ----------------
// lane i holds features (2i, 2i+1); head = i>>4; w/z redundant per head group.
// MODE 0: out fp16 [N,128] = relu(S/z + bias). MODE 1: out fp32 [N,32] = mean_heads + bias.
template <int MODE>
__global__ __launch_bounds__(256) void gat_agg(
    const _Float16* __restrict__ hx, const int* __restrict__ rowptr,
    const int* __restrict__ csr, const float* __restrict__ es,
    const float* __restrict__ ed, const float* __restrict__ bias,
    void* __restrict__ outp, int N) {
  int wid = (blockIdx.x * 256 + threadIdx.x) >> 6;
  if (wid >= N) return;
  int lane = threadIdx.x & 63;
  int beg = rowptr[wid], end = rowptr[wid + 1];
  int head = lane >> 4;
  float edv = ed[wid * 4 + head];
  float ax = 0.f, ay = 0.f, z = 0.f;
  int e = beg;
  for (; e + 4 <= end; e += 4) {
    int s0 = csr[e], s1 = csr[e + 1], s2 = csr[e + 2], s3 = csr[e + 3];
    float t0 = es[s0 * 4 + head], t1 = es[s1 * 4 + head];
    float t2 = es[s2 * 4 + head], t3 = es[s3 * 4 + head];
    f16x2 h0 = *(const f16x2*)(hx + (size_t)s0 * 128 + 2 * lane);
    f16x2 h1 = *(const f16x2*)(hx + (size_t)s1 * 128 + 2 * lane);
    f16x2 h2 = *(const f16x2*)(hx + (size_t)s2 * 128 + 2 * lane);
    f16x2 h3 = *(const f16x2*)(hx + (size_t)s3 * 128 + 2 * lane);
    t0 += edv; t1 += edv; t2 += edv; t3 += edv;
    t0 = t0 > 0.f ? t0 : NEG_SLOPE * t0;
    t1 = t1 > 0.f ? t1 : NEG_SLOPE * t1;
    t2 = t2 > 0.f ? t2 : NEG_SLOPE * t2;
    t3 = t3 > 0.f ? t3 : NEG_SLOPE * t3;
    float w0 = __expf(t0), w1 = __expf(t1), w2 = __expf(t2), w3 = __expf(t3);
    z += (w0 + w1) + (w2 + w3);
    ax = fmaf(w0, (float)h0[0], ax); ay = fmaf(w0, (float)h0[1], ay);
    ax = fmaf(w1, (float)h1[0], ax); ay = fmaf(w1, (float)h1[1], ay);
    ax = fmaf(w2, (float)h2[0], ax); ay = fmaf(w2, (float)h2[1], ay);
    ax = fmaf(w3, (float)h3[0], ax); ay = fmaf(w3, (float)h3[1], ay);
  }
  for (; e < end; ++e) {
    int s = csr[e];
    float t = es[s * 4 + head] + edv;
    t = t > 0.f ? t : NEG_SLOPE * t;
    float w = __expf(t);
    f16x2 hv = *(const f16x2*)(hx + (size_t)s * 128 + 2 * lane);
    ax = fmaf(w, (float)hv[0], ax);
    ay = fmaf(w, (float)hv[1], ay);
    z += w;
  }
  float inv = 1.f / (z + 1e-16f);
  float vx = ax * inv, vy = ay * inv;
  if (MODE == 0) {
    vx += bias[2 * lane]; vy += bias[2 * lane + 1];
    vx = vx > 0.f ? vx : 0.f;  vy = vy > 0.f ? vy : 0.f;
    f16x2 o; o[0] = (_Float16)vx; o[1] = (_Float16)vy;
    *(f16x2*)((_Float16*)outp + (size_t)wid * 128 + 2 * lane) = o;
  } else {
    vx += __shfl_xor(vx, 16); vx += __shfl_xor(vx, 32);
    vy += __shfl_xor(vy, 16); vy += __shfl_xor(vy, 32);
    if (lane < 16) {
      float ox = vx * 0.25f + bias[2 * lane];
      float oy = vy * 0.25f + bias[2 * lane + 1];
      *(float2*)((float*)outp + (size_t)wid * 32 + 2 * lane) = make_float2(ox, oy);
    }
  }
}

extern "C" void kernel_launch(void* const* d_in, const int* in_sizes, int n_in,
                              void* d_out, int out_size, void* d_ws, size_t ws_size,
                              hipStream_t stream) {
  const float* x   = (const float*)d_in[0];
  const int*   ei  = (const int*)d_in[1];
  const float* W1  = (const float*)d_in[2];
  const float* a1s = (const float*)d_in[3];
  const float* a1d = (const float*)d_in[4];
  const float* b1  = (const float*)d_in[5];
  const float* W2  = (const float*)d_in[6];
  const float* a2s = (const float*)d_in[7];
  const float* a2d = (const float*)d_in[8];
  const float* b2  = (const float*)d_in[9];
  const float* M1w = (const float*)d_in[10];
  const float* M1b = (const float*)d_in[11];
  const float* g1  = (const float*)d_in[12];
  const float* be1 = (const float*)d_in[13];
  const float* M2w = (const float*)d_in[14];
  const float* M2b = (const float*)d_in[15];
  const float* g2  = (const float*)d_in[16];
  const float* be2 = (const float*)d_in[17];
  const float* W3  = (const float*)d_in[18];
  const float* a3s = (const float*)d_in[19];
  const float* a3d = (const float*)d_in[20];
  const float* b3  = (const float*)d_in[21];

  const int N = in_sizes[0] / 128;
  const int E = in_sizes[1] / 2;

  char* w = (char*)d_ws;
  _Float16* bufA = (_Float16*)w; w += (size_t)N * 128 * 2;
  _Float16* bufB = (_Float16*)w; w += (size_t)N * 128 * 2;
  _Float16* bufM = (_Float16*)w; w += (size_t)N * 64 * 2;
  float* esb  = (float*)w; w += (size_t)N * 4 * 4;
  float* edb  = (float*)w; w += (size_t)N * 4 * 4;
  int* deg    = (int*)w;   w += (size_t)N * 4;
  int* inc    = (int*)w;   w += (size_t)N * 4;
  int* rowptr = (int*)w;   w += (size_t)(N + 1) * 4;
  int* pos    = (int*)w;   w += (size_t)N * 4;
  int* bsum   = (int*)w;   w += 256 * 4;
  int* csr    = (int*)w;   w += (size_t)(E + N) * 4;
  // split-fp16 transposed weights (hi/lo)
  _Float16* W1H = (_Float16*)w; w += 144 * 128 * 2;
  _Float16* W1L = (_Float16*)w; w += 144 * 128 * 2;
  _Float16* W2H = (_Float16*)w; w += 144 * 128 * 2;
  _Float16* W2L = (_Float16*)w; w += 144 * 128 * 2;
  _Float16* W3H = (_Float16*)w; w += 144 * 128 * 2;
  _Float16* W3L = (_Float16*)w; w += 144 * 128 * 2;
  _Float16* M1H = (_Float16*)w; w += 64 * 128 * 2;
  _Float16* M1L = (_Float16*)w; w += 64 * 128 * 2;
  _Float16* M2H = (_Float16*)w; w += 128 * 64 * 2;
  _Float16* M2L = (_Float16*)w; w += 128 * 64 * 2;

  const int nb = (N + 255) / 256;
  const int eb = (E + 255) / 256;
  const int gb = (N + 127) / 128;
  const int aggb = (N + 3) / 4;   // 4 waves per block

  // ---- weight prep (single dispatch) ----
  wprep_all<<<280, 256, 0, stream>>>(W1, a1s, a1d, W1H, W1L,
                                     W2, a2s, a2d, W2H, W2L,
                                     W3, a3s, a3d, W3H, W3L,
                                     M1w, M1H, M1L, M2w, M2H, M2L);

  // ---- CSR build (counting sort by dst; self-loop folded into scan3) ----
  deg_init<<<nb, 256, 0, stream>>>(deg, N);
  deg_count<<<eb, 256, 0, stream>>>(ei, deg, E);
  scan1<<<nb, 256, 0, stream>>>(deg, inc, bsum, N);
  scan2<<<1, 256, 0, stream>>>(bsum, nb);
  scan3<<<nb, 256, 0, stream>>>(inc, deg, bsum, rowptr, pos, csr, N);
  scatter_e<<<eb, 256, 0, stream>>>(ei, pos, csr, E);

  // ---- layer 0: conv0(+attn) -> agg(relu+bias) -> MLP x2 ----
  gemm_f16<144, 128, 128, 0, 1, float><<<gb, 256, 0, stream>>>(
      x, W1H, W1L, bufA, N, nullptr, nullptr, nullptr, esb, edb);
  gat_agg<0><<<aggb, 256, 0, stream>>>(bufA, rowptr, csr, esb, edb, b1, bufB, N);
  gemm_f16<64, 64, 128, 1, 0, _Float16><<<gb, 256, 0, stream>>>(
      bufB, M1H, M1L, bufM, N, M1b, g1, be1, nullptr, nullptr);
  gemm_f16<128, 128, 64, 1, 0, _Float16><<<gb, 256, 0, stream>>>(
      bufM, M2H, M2L, bufA, N, M2b, g2, be2, nullptr, nullptr);

  // ---- layer 1: conv1(+attn) -> agg(relu+bias) ----
  gemm_f16<144, 128, 128, 0, 1, _Float16><<<gb, 256, 0, stream>>>(
      bufA, W2H, W2L, bufB, N, nullptr, nullptr, nullptr, esb, edb);
  gat_agg<0><<<aggb, 256, 0, stream>>>(bufB, rowptr, csr, esb, edb, b2, bufA, N);

  // ---- layer 2: conv2(+attn) -> agg (mean heads, +b3) ----
  gemm_f16<144, 128, 128, 0, 1, _Float16><<<gb, 256, 0, stream>>>(
      bufA, W3H, W3L, bufB, N, nullptr, nullptr, nullptr, esb, edb);
  gat_agg<1><<<aggb, 256, 0, stream>>>(bufB, rowptr, csr, esb, edb, b3, d_out, N);
}

// Round 6
// 365.364 us; speedup vs baseline: 1.5827x; 1.1373x over previous
//
#include <hip/hip_runtime.h>
#include <hip/hip_bf16.h>

#define NEG_SLOPE 0.2f
#define BN_RS 0.9999950000374997f   // 1/sqrt(1 + 1e-5)

typedef __attribute__((ext_vector_type(8))) _Float16 f16x8;  // MFMA A/B frag (4 VGPR)
typedef __attribute__((ext_vector_type(2))) _Float16 f16x2;
typedef __attribute__((ext_vector_type(4))) float f32x4;     // MFMA acc

// split fp32 -> fp16 hi (RNE) + fp16 lo (RNE of residual); hi+lo carries ~22 bits
__device__ __forceinline__ void store_split(float w, _Float16* H, _Float16* L, size_t off) {
  _Float16 h = (_Float16)w;
  H[off] = h;
  L[off] = (_Float16)(w - (float)h);
}

// ---------------- CSR build: two-level bucket radix (bucket = dst>>8) ----------------
// Requires N <= 65536 (src packed into 16 bits). N = 50000 here.

__global__ void zero256(int* p) { p[threadIdx.x] = 0; }

__global__ void eb_hist(const int* __restrict__ ei, int* __restrict__ bucketSize, int E) {
  __shared__ int h[256];
  int tid = threadIdx.x;
  h[tid] = 0;
  __syncthreads();
  for (int i = blockIdx.x * 256 + tid; i < E; i += gridDim.x * 256)
    atomicAdd(&h[ei[E + i] >> 8], 1);
  __syncthreads();
  if (h[tid]) atomicAdd(&bucketSize[tid], h[tid]);
}

__global__ void eb_scan(const int* __restrict__ bucketSize, int* __restrict__ edgeStart,
                        int* __restrict__ cursor, int* __restrict__ csrStart, int N) {
  __shared__ int sd[256];
  int tid = threadIdx.x;
  int v = bucketSize[tid];
  sd[tid] = v;
  __syncthreads();
  for (int off = 1; off < 256; off <<= 1) {
    int t = (tid >= off) ? sd[tid - off] : 0;
    __syncthreads();
    sd[tid] += t;
    __syncthreads();
  }
  int excl = sd[tid] - v;
  edgeStart[tid] = excl;
  cursor[tid] = excl;
  csrStart[tid] = excl + min(tid << 8, N);
  if (tid == 255) edgeStart[256] = sd[255];
}

#define PCH 4096
__global__ __launch_bounds__(256) void eb_part(const int* __restrict__ ei,
                                               int* __restrict__ cursor,
                                               unsigned* __restrict__ staging, int E) {
  __shared__ unsigned val[PCH];
  __shared__ unsigned char bk[PCH];
  __shared__ int cnt[256];
  __shared__ int base[256];
  int tid = threadIdx.x;
  cnt[tid] = 0;
  __syncthreads();
  int e0 = blockIdx.x * PCH;
  int n = min(PCH, E - e0);
  for (int j = tid; j < n; j += 256) {
    int s = ei[e0 + j], d = ei[E + e0 + j];
    val[j] = ((unsigned)(d & 255) << 16) | (unsigned)s;
    int b = d >> 8;
    bk[j] = (unsigned char)b;
    atomicAdd(&cnt[b], 1);
  }
  __syncthreads();
  if (cnt[tid]) base[tid] = atomicAdd(&cursor[tid], cnt[tid]);
  __syncthreads();
  for (int j = tid; j < n; j += 256) {
    int b = bk[j];
    int off = atomicSub(&cnt[b], 1) - 1;
    staging[base[b] + off] = val[j];
  }
}

__global__ __launch_bounds__(256) void eb_csr(
    const unsigned* __restrict__ staging, const int* __restrict__ edgeStart,
    const int* __restrict__ csrStart, int* __restrict__ rowptr,
    int* __restrict__ csr, int N) {
  __shared__ int deg[256];
  __shared__ int sc[256];
  __shared__ int ex[256];
  int b = blockIdx.x, tid = threadIdx.x;
  int n0 = b << 8;
  int nn = min(256, N - n0);
  deg[tid] = (tid < nn) ? 1 : 0;   // self-loop
  __syncthreads();
  int s0 = edgeStart[b], s1 = edgeStart[b + 1];
  for (int j = s0 + tid; j < s1; j += 256)
    atomicAdd(&deg[staging[j] >> 16], 1);
  __syncthreads();
  int dv = deg[tid];
  sc[tid] = dv;
  __syncthreads();
  for (int off = 1; off < 256; off <<= 1) {
    int t = (tid >= off) ? sc[tid - off] : 0;
    __syncthreads();
    sc[tid] += t;
    __syncthreads();
  }
  int incl = sc[tid];
  int cbase = csrStart[b];
  ex[tid] = incl - dv;
  if (tid < nn) {
    rowptr[n0 + tid + 1] = cbase + incl;
    csr[cbase + incl - 1] = n0 + tid;   // self-loop at end of row
  }
  if (b == 0 && tid == 0) rowptr[0] = 0;
  deg[tid] = 0;                          // reuse as per-node cursor
  __syncthreads();
  for (int j = s0 + tid; j < s1; j += 256) {
    unsigned v = staging[j];
    int dl = v >> 16;
    int src = v & 0xFFFF;
    int off = atomicAdd(&deg[dl], 1);
    csr[cbase + ex[dl] + off] = src;
  }
}

// ---------------- weight prep ----------------
// conv W[128][128] -> Wt hi/lo fp16 [144][128]: rows 0..127 = W^T split,
// rows 128..131 = combined attn-src cols (es = A @ ws), 132..135 attn-dst, 136..143 zero.
// M1 [128][64] -> [64][128]; M2 [64][128] -> [128][64].
__device__ __forceinline__ void wprep_conv(const float* __restrict__ W,
                                           const float* __restrict__ as_,
                                           const float* __restrict__ ad_,
                                           _Float16* __restrict__ H, _Float16* __restrict__ L,
                                           int lb, int tid) {
  if (lb < 64) {                       // transpose region
    int idx = lb * 256 + tid;
    int k = idx >> 7, p = idx & 127;
    store_split(W[k * 128 + p], H, L, (size_t)p * 128 + k);
  } else if (lb < 68) {                // attn-combined rows
    int idx = (lb - 64) * 256 + tid;   // 1024 entries: 8 rows x 128 k
    int rl = idx >> 7, k = idx & 127;
    const float* a = (rl < 4) ? as_ : ad_;
    int h = rl & 3;
    float s = 0.f;
#pragma unroll
    for (int f = 0; f < 32; f++) s += W[k * 128 + h * 32 + f] * a[h * 32 + f];
    store_split(s, H, L, (size_t)(128 + rl) * 128 + k);
  } else {                             // zero pad rows 136..143
    int idx = (lb - 68) * 256 + tid;
    int rl = idx >> 7, k = idx & 127;
    H[(size_t)(136 + rl) * 128 + k] = (_Float16)0.f;
    L[(size_t)(136 + rl) * 128 + k] = (_Float16)0.f;
  }
}

__global__ void wprep_all(
    const float* __restrict__ W1, const float* __restrict__ a1s, const float* __restrict__ a1d,
    _Float16* __restrict__ W1H, _Float16* __restrict__ W1L,
    const float* __restrict__ W2, const float* __restrict__ a2s, const float* __restrict__ a2d,
    _Float16* __restrict__ W2H, _Float16* __restrict__ W2L,
    const float* __restrict__ W3, const float* __restrict__ a3s, const float* __restrict__ a3d,
    _Float16* __restrict__ W3H, _Float16* __restrict__ W3L,
    const float* __restrict__ M1, _Float16* __restrict__ M1H, _Float16* __restrict__ M1L,
    const float* __restrict__ M2, _Float16* __restrict__ M2H, _Float16* __restrict__ M2L) {
  int b = blockIdx.x, tid = threadIdx.x;
  if (b < 72)       wprep_conv(W1, a1s, a1d, W1H, W1L, b, tid);
  else if (b < 144) wprep_conv(W2, a2s, a2d, W2H, W2L, b - 72, tid);
  else if (b < 216) wprep_conv(W3, a3s, a3d, W3H, W3L, b - 144, tid);
  else if (b < 248) {                  // M1: [128][64] -> [64][128]
    int idx = (b - 216) * 256 + tid;
    int k = idx >> 6, p = idx & 63;
    store_split(M1[k * 64 + p], M1H, M1L, (size_t)p * 128 + k);
  } else {                             // M2: [64][128] -> [128][64]
    int idx = (b - 248) * 256 + tid;
    int k = idx >> 7, p = idx & 127;
    store_split(M2[k * 128 + p], M2H, M2L, (size_t)p * 64 + k);
  }
}

// ---------------- GEMM via fp16 MFMA, W split hi/lo ----------------
// C[N x PST](fp16) = A[N x K] @ W; A fp16 (or fp32 for layer 0, cvt in staging).
// D = A@Wh + A@Wl. AUG=1: PT=PST+16, extra tile -> es/ed fp32 (attn scores fused).
// EPI 0: raw store. EPI 1: bn(relu(acc + bias)).
template <int PT, int PST, int K, int EPI, int AUG, typename TA>
__global__ __launch_bounds__(256) void gemm_f16(
    const TA* __restrict__ A, const _Float16* __restrict__ WtH,
    const _Float16* __restrict__ WtL, _Float16* __restrict__ C, int N,
    const float* __restrict__ bias, const float* __restrict__ gamma,
    const float* __restrict__ beta, float* __restrict__ esb,
    float* __restrict__ edb) {
  constexpr int NTILE = PT / 16;
  constexpr int CTB = NTILE / 4;      // base col-tiles per wave
  constexpr int REM = NTILE % 4;      // 0 or 1 (extra tile on wave 0)
  constexpr int KT = K / 32;
  __shared__ _Float16 As[128 * 32];
  __shared__ _Float16 WsH[PT * 32];
  __shared__ _Float16 WsL[PT * 32];
  const int tid = threadIdx.x;
  const int wave = tid >> 6, lane = tid & 63;
  const int quad = lane >> 4, l16 = lane & 15;
  const int row0 = blockIdx.x * 128;
  const bool xw = (REM != 0) && (wave == 0);

  f32x4 acc[8][CTB + (REM ? 1 : 0)];
#pragma unroll
  for (int rt = 0; rt < 8; rt++)
#pragma unroll
    for (int nt = 0; nt < CTB + (REM ? 1 : 0); nt++) acc[rt][nt] = (f32x4){0.f, 0.f, 0.f, 0.f};

  for (int kc = 0; kc < KT; ++kc) {
    // ---- stage A: 128 rows x 32 halves ----
    {
      int r = tid >> 1, part = tid & 1;
      int gr = row0 + r;
      _Float16* dst = &As[r * 32 + part * 16];
      if (gr < N) {
        const TA* src = A + (size_t)gr * K + kc * 32 + part * 16;
        if constexpr (sizeof(TA) == 4) {     // fp32 input (layer 0): cvt
          f16x8 h0, h1;
#pragma unroll
          for (int j = 0; j < 8; j++) { h0[j] = (_Float16)src[j]; h1[j] = (_Float16)src[8 + j]; }
          *(f16x8*)dst = h0; *(f16x8*)(dst + 8) = h1;
        } else {                              // fp16: raw copy
          uint4 v0 = *(const uint4*)src;
          uint4 v1 = *(const uint4*)(src + 8);
          *(uint4*)dst = v0; *(uint4*)(dst + 8) = v1;
        }
      } else {
        *(uint4*)dst = make_uint4(0, 0, 0, 0);
        *(uint4*)(dst + 8) = make_uint4(0, 0, 0, 0);
      }
    }
    // ---- stage W hi/lo: PT rows x 32 halves each ----
    for (int idx = tid; idx < PT * 2; idx += 256) {
      int isL = idx >= PT;
      int p = isL ? idx - PT : idx;
      const _Float16* src = (isL ? WtL : WtH) + (size_t)p * K + kc * 32;
      _Float16* dst = (isL ? WsL : WsH) + p * 32;
      uint4 a0 = *(const uint4*)src;       uint4 a1 = *(const uint4*)(src + 8);
      uint4 a2 = *(const uint4*)(src + 16); uint4 a3 = *(const uint4*)(src + 24);
      *(uint4*)dst = a0; *(uint4*)(dst + 8) = a1;
      *(uint4*)(dst + 16) = a2; *(uint4*)(dst + 24) = a3;
    }
    __syncthreads();

    f16x8 bh[CTB], bl[CTB], bhE, blE;
#pragma unroll
    for (int nt = 0; nt < CTB; nt++) {
      int p = (wave * CTB + nt) * 16 + l16;
      bh[nt] = *(f16x8*)&WsH[p * 32 + quad * 8];
      bl[nt] = *(f16x8*)&WsL[p * 32 + quad * 8];
    }
    if constexpr (REM) {
      if (xw) {
        int p = 4 * CTB * 16 + l16;
        bhE = *(f16x8*)&WsH[p * 32 + quad * 8];
        blE = *(f16x8*)&WsL[p * 32 + quad * 8];
      }
    }
#pragma unroll
    for (int rt = 0; rt < 8; rt++) {
      f16x8 a = *(f16x8*)&As[(rt * 16 + l16) * 32 + quad * 8];
#pragma unroll
      for (int nt = 0; nt < CTB; nt++) {
        acc[rt][nt] = __builtin_amdgcn_mfma_f32_16x16x32_f16(a, bh[nt], acc[rt][nt], 0, 0, 0);
        acc[rt][nt] = __builtin_amdgcn_mfma_f32_16x16x32_f16(a, bl[nt], acc[rt][nt], 0, 0, 0);
      }
      if constexpr (REM) {
        if (xw) {
          acc[rt][CTB] = __builtin_amdgcn_mfma_f32_16x16x32_f16(a, bhE, acc[rt][CTB], 0, 0, 0);
          acc[rt][CTB] = __builtin_amdgcn_mfma_f32_16x16x32_f16(a, blE, acc[rt][CTB], 0, 0, 0);
        }
      }
    }
    __syncthreads();
  }

  // ---- epilogue (C/D layout: col=lane&15, row=quad*4+reg) ----
#pragma unroll
  for (int nt = 0; nt < CTB; nt++) {
    int c = (wave * CTB + nt) * 16 + l16;
    float bi = 0.f, ga = 0.f, be = 0.f;
    if constexpr (EPI == 1) { bi = bias[c]; ga = gamma[c] * BN_RS; be = beta[c]; }
#pragma unroll
    for (int rt = 0; rt < 8; rt++)
#pragma unroll
      for (int g = 0; g < 4; g++) {
        int r = row0 + rt * 16 + quad * 4 + g;
        if (r < N) {
          float v = acc[rt][nt][g];
          if constexpr (EPI == 1) { v += bi; v = v > 0.f ? v : 0.f; v = v * ga + be; }
          C[(size_t)r * PST + c] = (_Float16)v;
        }
      }
  }
  if constexpr (REM) {
    if (wave == 0 && l16 < 8) {
      float* dstb = (l16 < 4) ? esb : edb;
      int h = l16 & 3;
#pragma unroll
      for (int rt = 0; rt < 8; rt++)
#pragma unroll
        for (int g = 0; g < 4; g++) {
          int r = row0 + rt * 16 + quad * 4 + g;
          if (r < N) dstb[(size_t)r * 4 + h] = acc[rt][CTB][g];
        }
    }
  }
}

// ---------------- GAT aggregation: one wave per dst node, fp16 h ----------------
// lane i holds features (2i, 2i+1); head = i>>4; w/z redundant per head group.
// MODE 0: out fp16 [N,128] = relu(S/z + bias). MODE 1: out fp32 [N,32] = mean_heads + bias.
template <int MODE>
__global__ __launch_bounds__(256) void gat_agg(
    const _Float16* __restrict__ hx, const int* __restrict__ rowptr,
    const int* __restrict__ csr, const float* __restrict__ es,
    const float* __restrict__ ed, const float* __restrict__ bias,
    void* __restrict__ outp, int N) {
  int wid = (blockIdx.x * 256 + threadIdx.x) >> 6;
  if (wid >= N) return;
  int lane = threadIdx.x & 63;
  int beg = rowptr[wid], end = rowptr[wid + 1];
  int head = lane >> 4;
  float edv = ed[wid * 4 + head];
  float ax = 0.f, ay = 0.f, z = 0.f;
  int e = beg;
  for (; e + 4 <= end; e += 4) {
    int s0 = csr[e], s1 = csr[e + 1], s2 = csr[e + 2], s3 = csr[e + 3];
    float t0 = es[s0 * 4 + head], t1 = es[s1 * 4 + head];
    float t2 = es[s2 * 4 + head], t3 = es[s3 * 4 + head];
    f16x2 h0 = *(const f16x2*)(hx + (size_t)s0 * 128 + 2 * lane);
    f16x2 h1 = *(const f16x2*)(hx + (size_t)s1 * 128 + 2 * lane);
    f16x2 h2 = *(const f16x2*)(hx + (size_t)s2 * 128 + 2 * lane);
    f16x2 h3 = *(const f16x2*)(hx + (size_t)s3 * 128 + 2 * lane);
    t0 += edv; t1 += edv; t2 += edv; t3 += edv;
    t0 = t0 > 0.f ? t0 : NEG_SLOPE * t0;
    t1 = t1 > 0.f ? t1 : NEG_SLOPE * t1;
    t2 = t2 > 0.f ? t2 : NEG_SLOPE * t2;
    t3 = t3 > 0.f ? t3 : NEG_SLOPE * t3;
    float w0 = __expf(t0), w1 = __expf(t1), w2 = __expf(t2), w3 = __expf(t3);
    z += (w0 + w1) + (w2 + w3);
    ax = fmaf(w0, (float)h0[0], ax); ay = fmaf(w0, (float)h0[1], ay);
    ax = fmaf(w1, (float)h1[0], ax); ay = fmaf(w1, (float)h1[1], ay);
    ax = fmaf(w2, (float)h2[0], ax); ay = fmaf(w2, (float)h2[1], ay);
    ax = fmaf(w3, (float)h3[0], ax); ay = fmaf(w3, (float)h3[1], ay);
  }
  for (; e < end; ++e) {
    int s = csr[e];
    float t = es[s * 4 + head] + edv;
    t = t > 0.f ? t : NEG_SLOPE * t;
    float w = __expf(t);
    f16x2 hv = *(const f16x2*)(hx + (size_t)s * 128 + 2 * lane);
    ax = fmaf(w, (float)hv[0], ax);
    ay = fmaf(w, (float)hv[1], ay);
    z += w;
  }
  float inv = 1.f / (z + 1e-16f);
  float vx = ax * inv, vy = ay * inv;
  if (MODE == 0) {
    vx += bias[2 * lane]; vy += bias[2 * lane + 1];
    vx = vx > 0.f ? vx : 0.f;  vy = vy > 0.f ? vy : 0.f;
    f16x2 o; o[0] = (_Float16)vx; o[1] = (_Float16)vy;
    *(f16x2*)((_Float16*)outp + (size_t)wid * 128 + 2 * lane) = o;
  } else {
    vx += __shfl_xor(vx, 16); vx += __shfl_xor(vx, 32);
    vy += __shfl_xor(vy, 16); vy += __shfl_xor(vy, 32);
    if (lane < 16) {
      float ox = vx * 0.25f + bias[2 * lane];
      float oy = vy * 0.25f + bias[2 * lane + 1];
      *(float2*)((float*)outp + (size_t)wid * 32 + 2 * lane) = make_float2(ox, oy);
    }
  }
}

extern "C" void kernel_launch(void* const* d_in, const int* in_sizes, int n_in,
                              void* d_out, int out_size, void* d_ws, size_t ws_size,
                              hipStream_t stream) {
  const float* x   = (const float*)d_in[0];
  const int*   ei  = (const int*)d_in[1];
  const float* W1  = (const float*)d_in[2];
  const float* a1s = (const float*)d_in[3];
  const float* a1d = (const float*)d_in[4];
  const float* b1  = (const float*)d_in[5];
  const float* W2  = (const float*)d_in[6];
  const float* a2s = (const float*)d_in[7];
  const float* a2d = (const float*)d_in[8];
  const float* b2  = (const float*)d_in[9];
  const float* M1w = (const float*)d_in[10];
  const float* M1b = (const float*)d_in[11];
  const float* g1  = (const float*)d_in[12];
  const float* be1 = (const float*)d_in[13];
  const float* M2w = (const float*)d_in[14];
  const float* M2b = (const float*)d_in[15];
  const float* g2  = (const float*)d_in[16];
  const float* be2 = (const float*)d_in[17];
  const float* W3  = (const float*)d_in[18];
  const float* a3s = (const float*)d_in[19];
  const float* a3d = (const float*)d_in[20];
  const float* b3  = (const float*)d_in[21];

  const int N = in_sizes[0] / 128;
  const int E = in_sizes[1] / 2;

  char* w = (char*)d_ws;
  _Float16* bufA = (_Float16*)w; w += (size_t)N * 128 * 2;
  _Float16* bufB = (_Float16*)w; w += (size_t)N * 128 * 2;
  _Float16* bufM = (_Float16*)w; w += (size_t)N * 64 * 2;
  float* esb  = (float*)w; w += (size_t)N * 4 * 4;
  float* edb  = (float*)w; w += (size_t)N * 4 * 4;
  int* rowptr = (int*)w;   w += (size_t)(N + 1) * 4;
  int* csr    = (int*)w;   w += (size_t)(E + N) * 4;
  unsigned* staging = (unsigned*)w; w += (size_t)E * 4;
  int* bucketSize = (int*)w; w += 256 * 4;
  int* edgeStart  = (int*)w; w += 257 * 4;
  int* cursor     = (int*)w; w += 256 * 4;
  int* csrStart   = (int*)w; w += 256 * 4;
  // split-fp16 transposed weights (hi/lo)
  _Float16* W1H = (_Float16*)w; w += 144 * 128 * 2;
  _Float16* W1L = (_Float16*)w; w += 144 * 128 * 2;
  _Float16* W2H = (_Float16*)w; w += 144 * 128 * 2;
  _Float16* W2L = (_Float16*)w; w += 144 * 128 * 2;
  _Float16* W3H = (_Float16*)w; w += 144 * 128 * 2;
  _Float16* W3L = (_Float16*)w; w += 144 * 128 * 2;
  _Float16* M1H = (_Float16*)w; w += 64 * 128 * 2;
  _Float16* M1L = (_Float16*)w; w += 64 * 128 * 2;
  _Float16* M2H = (_Float16*)w; w += 128 * 64 * 2;
  _Float16* M2L = (_Float16*)w; w += 128 * 64 * 2;

  const int gb = (N + 127) / 128;
  const int aggb = (N + 3) / 4;        // 4 waves per block
  const int nbk = (N + 255) / 256;     // buckets
  const int pbk = (E + PCH - 1) / PCH;

  // ---- weight prep (single dispatch) ----
  wprep_all<<<280, 256, 0, stream>>>(W1, a1s, a1d, W1H, W1L,
                                     W2, a2s, a2d, W2H, W2L,
                                     W3, a3s, a3d, W3H, W3L,
                                     M1w, M1H, M1L, M2w, M2H, M2L);

  // ---- CSR build: bucket radix partition ----
  zero256<<<1, 256, 0, stream>>>(bucketSize);
  eb_hist<<<256, 256, 0, stream>>>(ei, bucketSize, E);
  eb_scan<<<1, 256, 0, stream>>>(bucketSize, edgeStart, cursor, csrStart, N);
  eb_part<<<pbk, 256, 0, stream>>>(ei, cursor, staging, E);
  eb_csr<<<nbk, 256, 0, stream>>>(staging, edgeStart, csrStart, rowptr, csr, N);

  // ---- layer 0: conv0(+attn) -> agg(relu+bias) -> MLP x2 ----
  gemm_f16<144, 128, 128, 0, 1, float><<<gb, 256, 0, stream>>>(
      x, W1H, W1L, bufA, N, nullptr, nullptr, nullptr, esb, edb);
  gat_agg<0><<<aggb, 256, 0, stream>>>(bufA, rowptr, csr, esb, edb, b1, bufB, N);
  gemm_f16<64, 64, 128, 1, 0, _Float16><<<gb, 256, 0, stream>>>(
      bufB, M1H, M1L, bufM, N, M1b, g1, be1, nullptr, nullptr);
  gemm_f16<128, 128, 64, 1, 0, _Float16><<<gb, 256, 0, stream>>>(
      bufM, M2H, M2L, bufA, N, M2b, g2, be2, nullptr, nullptr);

  // ---- layer 1: conv1(+attn) -> agg(relu+bias) ----
  gemm_f16<144, 128, 128, 0, 1, _Float16><<<gb, 256, 0, stream>>>(
      bufA, W2H, W2L, bufB, N, nullptr, nullptr, nullptr, esb, edb);
  gat_agg<0><<<aggb, 256, 0, stream>>>(bufB, rowptr, csr, esb, edb, b2, bufA, N);

  // ---- layer 2: conv2(+attn) -> agg (mean heads, +b3) ----
  gemm_f16<144, 128, 128, 0, 1, _Float16><<<gb, 256, 0, stream>>>(
      bufA, W3H, W3L, bufB, N, nullptr, nullptr, nullptr, esb, edb);
  gat_agg<1><<<aggb, 256, 0, stream>>>(bufB, rowptr, csr, esb, edb, b3, d_out, N);
}